// Round 1
// baseline (49799.118 us; speedup 1.0000x reference)
//
#include <hip/hip_runtime.h>
#include <hip/hip_bf16.h>
#include <stdint.h>

// Neural ODE (RK4, 32 steps) over a 5-layer MLP, B=32768, VAR_DIM=50 (pad 64).
// Strategy: bf16 MFMA GEMMs (16x16x32), fp32 accum, fp32 state y.
// concat(h,t) @ W  ==  h @ W[:K] + (b + t*W[K])  -> time column folded into bias.
// Weights pre-transposed to N x K bf16 once per launch (reused 128x).

typedef __bf16 bf16_t;
typedef bf16_t bf16x8 __attribute__((ext_vector_type(8)));
typedef float  f32x4  __attribute__((ext_vector_type(4)));

#define DEVI static __device__ __forceinline__

DEVI void gload_lds16(const bf16_t* gsrc, bf16_t* ldst) {
  // async global->LDS, 16B per lane; LDS dest is wave-uniform base + lane*16
  __builtin_amdgcn_global_load_lds(
      (const __attribute__((address_space(1))) uint32_t*)gsrc,
      (__attribute__((address_space(3))) uint32_t*)ldst,
      16, 0, 0);
}

// C(M x N) = A(M x K, bf16 row-major) * BT(N x K, bf16 row-major)^T + (bias + t*wtime)
// optional ReLU; output bf16 (next activation) or fp32 (k buffer).
template<int BM, int BN, int BK, int WROWS, int WCOLS, bool RELU, bool OUT_BF16>
__global__ __launch_bounds__(256) void gemm_bt(
    const bf16_t* __restrict__ A, int lda,
    const bf16_t* __restrict__ BT,          // ld = K
    const float* __restrict__ bias,
    const float* __restrict__ wtime,
    float t,
    void* __restrict__ Cv, int ldc,
    int M, int K)
{
  constexpr int MR  = BM / WROWS / 16;
  constexpr int NR  = BN / WCOLS / 16;
  constexpr int TPR = BK / 8;        // threads per row for staging
  constexpr int RPW = 64 / TPR;      // rows staged per wave per load
  constexpr int RPL = 4 * RPW;       // rows staged per load instr (4 waves)
  static_assert(BM % RPL == 0 && BN % RPL == 0, "tile staging mismatch");

  __shared__ bf16_t As[BM][BK];
  __shared__ bf16_t Bs[BN][BK];

  const int tid  = threadIdx.x;
  const int wave = tid >> 6;
  const int lane = tid & 63;
  const int wr = wave / WCOLS;
  const int wc = wave % WCOLS;

  const int bm = blockIdx.x * BM;
  const int bn = blockIdx.y * BN;

  const int lrow = lane / TPR;
  const int lcol = (lane % TPR) * 8;

  f32x4 acc[MR][NR] = {};

  for (int k0 = 0; k0 < K; k0 += BK) {
#pragma unroll
    for (int i = 0; i < BM / RPL; ++i) {
      const int rb = i * RPL + wave * RPW;
      gload_lds16(&A[(size_t)(bm + rb + lrow) * lda + k0 + lcol], &As[rb][0]);
    }
#pragma unroll
    for (int i = 0; i < BN / RPL; ++i) {
      const int rb = i * RPL + wave * RPW;
      gload_lds16(&BT[(size_t)(bn + rb + lrow) * K + k0 + lcol], &Bs[rb][0]);
    }
    __syncthreads();   // drains vmcnt -> staged data visible

#pragma unroll
    for (int kk = 0; kk < BK / 32; ++kk) {
      bf16x8 af[MR], bfr[NR];
#pragma unroll
      for (int m = 0; m < MR; ++m)
        af[m] = *(const bf16x8*)&As[wr * (BM / WROWS) + m * 16 + (lane & 15)]
                                  [kk * 32 + (lane >> 4) * 8];
#pragma unroll
      for (int n = 0; n < NR; ++n)
        bfr[n] = *(const bf16x8*)&Bs[wc * (BN / WCOLS) + n * 16 + (lane & 15)]
                                    [kk * 32 + (lane >> 4) * 8];
#pragma unroll
      for (int m = 0; m < MR; ++m)
#pragma unroll
        for (int n = 0; n < NR; ++n)
          acc[m][n] = __builtin_amdgcn_mfma_f32_16x16x32_bf16(
              af[m], bfr[n], acc[m][n], 0, 0, 0);
    }
    __syncthreads();   // protect LDS before next stage overwrites
  }

  // epilogue: bias(t) + optional ReLU; C/D frag: col=lane&15, row=(lane>>4)*4+r
#pragma unroll
  for (int n = 0; n < NR; ++n) {
    const int gcol = bn + wc * (BN / WCOLS) + n * 16 + (lane & 15);
    const float bv = bias[gcol] + t * wtime[gcol];
#pragma unroll
    for (int m = 0; m < MR; ++m) {
      const int grow0 = bm + wr * (BM / WROWS) + m * 16 + ((lane >> 4) << 2);
#pragma unroll
      for (int r = 0; r < 4; ++r) {
        float v = acc[m][n][r] + bv;
        if (RELU) v = v > 0.0f ? v : 0.0f;
        if constexpr (OUT_BF16)
          ((bf16_t*)Cv)[(size_t)(grow0 + r) * ldc + gcol] = (bf16_t)v;
        else
          ((float*)Cv)[(size_t)(grow0 + r) * ldc + gcol] = v;
      }
    }
  }
}

// W (K+1 x N fp32, row-major) -> WT (Npad x Kpad bf16, zero-padded, transposed)
// bias[n] = b[n], wtime[n] = W[K][n] (the time-column row), zero-padded.
__global__ void prep_weight(const float* __restrict__ W, const float* __restrict__ b,
                            bf16_t* __restrict__ WT, float* __restrict__ bias,
                            float* __restrict__ wtime,
                            int K, int N, int Kpad, int Npad)
{
  int idx = blockIdx.x * 256 + threadIdx.x;
  int total = Npad * Kpad;
  if (idx < total) {
    int n = idx / Kpad, k = idx % Kpad;
    float v = (n < N && k < K) ? W[(size_t)k * N + n] : 0.0f;
    WT[idx] = (bf16_t)v;
  }
  if (idx < Npad) {
    bias[idx]  = (idx < N) ? b[idx] : 0.0f;
    wtime[idx] = (idx < N) ? W[(size_t)K * N + idx] : 0.0f;
  }
}

// y[:, :2] = x, rest 0 (fp32 state, stride 64); ybf = bf16(y)
__global__ void init_y(const float* __restrict__ x, float* __restrict__ y,
                       bf16_t* __restrict__ ybf, int M)
{
  int i = blockIdx.x * 256 + threadIdx.x;
  if (i < M * 64) {
    int m = i >> 6, c = i & 63;
    float v = (c < 2) ? x[m * 2 + c] : 0.0f;
    y[i] = v;
    ybf[i] = (bf16_t)v;
  }
}

// mode 0: acc = k;            ybf = bf16(y + cstep*k)
// mode 1: acc += cacc*k;      ybf = bf16(y + cstep*k)
// mode 2: y += cstep*(acc+k); ybf = bf16(y)
__global__ void rk4_combine(float* __restrict__ y, float* __restrict__ acc,
                            const float* __restrict__ k,
                            bf16_t* __restrict__ ybf,
                            float cacc, float cstep, int mode, int M)
{
  int i = blockIdx.x * 256 + threadIdx.x;
  if (i >= M * 64) return;
  float kv = k[i];
  if (mode == 0) {
    acc[i] = kv;
    ybf[i] = (bf16_t)(y[i] + cstep * kv);
  } else if (mode == 1) {
    acc[i] += cacc * kv;
    ybf[i] = (bf16_t)(y[i] + cstep * kv);
  } else {
    float ny = y[i] + cstep * (acc[i] + kv);
    y[i] = ny;
    ybf[i] = (bf16_t)ny;
  }
}

__global__ void extract_out(const float* __restrict__ y, float* __restrict__ out, int M)
{
  int i = blockIdx.x * 256 + threadIdx.x;
  if (i < M * 3) {
    int m = i / 3, c = i % 3;
    out[i] = y[(size_t)m * 64 + c];
  }
}

extern "C" void kernel_launch(void* const* d_in, const int* in_sizes, int n_in,
                              void* d_out, int out_size, void* d_ws, size_t ws_size,
                              hipStream_t stream)
{
  (void)in_sizes; (void)n_in; (void)out_size; (void)ws_size;
  const int M = 32768;

  const float* x = (const float*)d_in[0];
  const float* Wp[5]; const float* bp[5];
  for (int i = 0; i < 5; ++i) {
    Wp[i] = (const float*)d_in[1 + 2 * i];
    bp[i] = (const float*)d_in[2 + 2 * i];
  }

  char* ws = (char*)d_ws; size_t off = 0;
  auto alloc = [&](size_t bytes) -> char* {
    char* p = ws + off; off += (bytes + 255) & ~(size_t)255; return p;
  };

  bf16_t* WT[5];
  WT[0] = (bf16_t*)alloc((size_t)1024 * 64 * 2);
  WT[1] = (bf16_t*)alloc((size_t)1024 * 1024 * 2);
  WT[2] = (bf16_t*)alloc((size_t)1024 * 1024 * 2);
  WT[3] = (bf16_t*)alloc((size_t)1024 * 1024 * 2);
  WT[4] = (bf16_t*)alloc((size_t)64 * 1024 * 2);
  float* bias[5]; float* wtm[5];
  for (int i = 0; i < 5; ++i) {
    int Np = (i == 4) ? 64 : 1024;
    bias[i] = (float*)alloc((size_t)Np * 4);
    wtm[i]  = (float*)alloc((size_t)Np * 4);
  }
  float*  y    = (float*)alloc((size_t)M * 64 * 4);
  float*  accb = (float*)alloc((size_t)M * 64 * 4);
  float*  kbuf = (float*)alloc((size_t)M * 64 * 4);
  bf16_t* ybf  = (bf16_t*)alloc((size_t)M * 64 * 2);
  bf16_t* act0 = (bf16_t*)alloc((size_t)M * 1024 * 2);
  bf16_t* act1 = (bf16_t*)alloc((size_t)M * 1024 * 2);

  const int Kd[5]   = {50, 1024, 1024, 1024, 1024};
  const int Nd[5]   = {1024, 1024, 1024, 1024, 50};
  const int Kpd[5]  = {64, 1024, 1024, 1024, 1024};
  const int Npd[5]  = {1024, 1024, 1024, 1024, 64};
  for (int i = 0; i < 5; ++i) {
    int tot = Npd[i] * Kpd[i];
    prep_weight<<<dim3((tot + 255) / 256), 256, 0, stream>>>(
        Wp[i], bp[i], WT[i], bias[i], wtm[i], Kd[i], Nd[i], Kpd[i], Npd[i]);
  }

  init_y<<<dim3((M * 64 + 255) / 256), 256, 0, stream>>>(x, y, ybf, M);

  const float dtv = 1.0f / 32.0f;
  dim3 gBig(M / 128, 1024 / 128);
  dim3 gL4(M / 256, 1);
  dim3 gCmb((M * 64) / 256);

  auto run_net = [&](float t) {
    gemm_bt<128,128,64,2,2,true ,true ><<<gBig, 256, 0, stream>>>(
        ybf, 64, WT[0], bias[0], wtm[0], t, act0, 1024, M, 64);
    gemm_bt<128,128,64,2,2,true ,true ><<<gBig, 256, 0, stream>>>(
        act0, 1024, WT[1], bias[1], wtm[1], t, act1, 1024, M, 1024);
    gemm_bt<128,128,64,2,2,true ,true ><<<gBig, 256, 0, stream>>>(
        act1, 1024, WT[2], bias[2], wtm[2], t, act0, 1024, M, 1024);
    gemm_bt<128,128,64,2,2,true ,true ><<<gBig, 256, 0, stream>>>(
        act0, 1024, WT[3], bias[3], wtm[3], t, act1, 1024, M, 1024);
    gemm_bt<256, 64,64,4,1,false,false><<<gL4 , 256, 0, stream>>>(
        act1, 1024, WT[4], bias[4], wtm[4], t, kbuf, 64, M, 1024);
  };

  for (int i = 0; i < 32; ++i) {
    float t0 = i * dtv;
    float tm = t0 + 0.5f * dtv;
    float t1 = t0 + dtv;
    run_net(t0);  // k1
    rk4_combine<<<gCmb, 256, 0, stream>>>(y, accb, kbuf, ybf, 0.0f, 0.5f * dtv, 0, M);
    run_net(tm);  // k2
    rk4_combine<<<gCmb, 256, 0, stream>>>(y, accb, kbuf, ybf, 2.0f, 0.5f * dtv, 1, M);
    run_net(tm);  // k3
    rk4_combine<<<gCmb, 256, 0, stream>>>(y, accb, kbuf, ybf, 2.0f, dtv, 1, M);
    run_net(t1);  // k4
    rk4_combine<<<gCmb, 256, 0, stream>>>(y, accb, kbuf, ybf, 0.0f, dtv / 6.0f, 2, M);
  }

  extract_out<<<dim3((M * 3 + 255) / 256), 256, 0, stream>>>(y, (float*)d_out, M);
}

// Round 2
// 40941.556 us; speedup vs baseline: 1.2163x; 1.2163x over previous
//
#include <hip/hip_runtime.h>
#include <hip/hip_bf16.h>
#include <stdint.h>

// Neural ODE (RK4, 32 steps) over a 5-layer MLP, B=32768, VAR_DIM=50 (pad 64).
// bf16 MFMA GEMMs (16x16x32), fp32 accum, fp32 state y.
// concat(h,t) @ W == h @ W[:K] + (b + t*W[K]) -> time column folded into bias.
// Layers 1-3: 256^2/8-wave/8-phase pipelined GEMM (T1+T2+T3+T4+T5).
// Layer 4 (N=64): 128x64 GEMM with RK4 combine fused into the epilogue.

typedef __bf16 bf16_t;
typedef bf16_t bf16x8 __attribute__((ext_vector_type(8)));
typedef float  f32x4  __attribute__((ext_vector_type(4)));

#define DEVI static __device__ __forceinline__

DEVI void gload_lds16(const bf16_t* gsrc, bf16_t* ldst) {
  __builtin_amdgcn_global_load_lds(
      (const __attribute__((address_space(1))) uint32_t*)gsrc,
      (__attribute__((address_space(3))) uint32_t*)ldst,
      16, 0, 0);
}

// ---------------------------------------------------------------------------
// 256x256 tile, BK=64, 8 waves (2Mx4N), double-buffered LDS, 8-phase schedule.
// LDS st_16x32 swizzle: linear dest via global_load_lds + pre-swizzled SOURCE
// col (elem c ^ 16 when dest row&4) + same XOR on ds_read byte addr.
// vmcnt(6) once per K-tile (3 half-tiles in flight); drain to 0 in epilogue.
// ---------------------------------------------------------------------------
template<int K>
__global__ __launch_bounds__(512, 2) void gemm256(
    const bf16_t* __restrict__ A,     // M x K row-major
    const bf16_t* __restrict__ BT,    // N x K row-major (pre-transposed W)
    const float* __restrict__ bias,
    const float* __restrict__ wtime,
    float t,
    bf16_t* __restrict__ C, int ldc,
    int M, int N)
{
  constexpr int NT = K / 64;          // K-tiles
  static_assert(NT >= 2, "need >=2 K-tiles");

  __shared__ __align__(16) bf16_t As[2][256][64];
  __shared__ __align__(16) bf16_t Bs[2][256][64];

  const int tid  = threadIdx.x;
  const int wave = tid >> 6;
  const int lane = tid & 63;
  const int wr = wave >> 2;           // 0..1 -> 128-row half
  const int wc = wave & 3;            // 0..3 -> 64-col strip

  // T1: XCD-aware bijective swizzle (gridDim.x % 8 == 0 by construction)
  int wg = blockIdx.x;
  {
    const int cpx = gridDim.x >> 3;
    wg = (wg & 7) * cpx + (wg >> 3);
  }
  const int nbn = N >> 8;
  const int bm = (wg / nbn) << 8;
  const int bn = (wg % nbn) << 8;

  // staging: thread -> (row = tid/8 within 64-row slab, 16B col chunk)
  const int srow = lane >> 3;
  const int scol = ((lane & 7) << 3) ^ ((lane & 32) >> 1);  // pre-swizzled src col
  const bf16_t* aS = A  + (size_t)(bm + wave * 8 + srow) * K + scol;
  const bf16_t* bS = BT + (size_t)(bn + wave * 8 + srow) * K + scol;
  bf16_t* aD = &As[0][0][0] + wave * 8 * 64;   // wave-uniform LDS base
  bf16_t* bD = &Bs[0][0][0] + wave * 8 * 64;

  // half-tile g: ktile=g/4, idx g&3: 0=A-h0 1=B-h0 2=A-h1 3=B-h1
  auto stage = [&](int g) {
    if (g >= 4 * NT) return;
    const int kt   = g >> 2;
    const int idx  = g & 3;
    const int hoff = (idx >> 1) << 7;           // 0 or 128 rows
    const int buf  = kt & 1;
    const bf16_t* src = (idx & 1) ? bS : aS;
    bf16_t*       dst = (idx & 1) ? bD : aD;
    src += (size_t)hoff * K + kt * 64;
    dst += (buf * 256 + hoff) * 64;
    gload_lds16(src,                dst);
    gload_lds16(src + (size_t)64*K, dst + 64 * 64);
  };

  const int fr = lane & 15;
  const int fq = lane >> 4;

  bf16x8 af[8];        // A quadrant frags [m*2+kk]
  bf16x8 bfr[8];       // B frags [nh*4 + n*2 + kk]
  f32x4  acc[8][4] = {};

  auto lda_frag = [&](int buf, int mh) {
    const char* base = (const char*)&As[buf][0][0];
#pragma unroll
    for (int m = 0; m < 4; ++m)
#pragma unroll
      for (int kk = 0; kk < 2; ++kk) {
        int r  = wr * 128 + (mh * 4 + m) * 16 + fr;
        int cb = (kk * 64 + fq * 16) ^ ((r & 4) << 3);
        af[m * 2 + kk] = *(const bf16x8*)(base + r * 128 + cb);
      }
  };
  auto ldb_frag = [&](int buf, int nh) {
    const char* base = (const char*)&Bs[buf][0][0];
#pragma unroll
    for (int n = 0; n < 2; ++n)
#pragma unroll
      for (int kk = 0; kk < 2; ++kk) {
        int r  = wc * 64 + (nh * 2 + n) * 16 + fr;
        int cb = (kk * 64 + fq * 16) ^ ((r & 4) << 3);
        bfr[nh * 4 + n * 2 + kk] = *(const bf16x8*)(base + r * 128 + cb);
      }
  };
  auto mma_quad = [&](int mh, int nh) {
    __builtin_amdgcn_s_setprio(1);
#pragma unroll
    for (int m = 0; m < 4; ++m)
#pragma unroll
      for (int n = 0; n < 2; ++n)
#pragma unroll
        for (int kk = 0; kk < 2; ++kk)
          acc[mh * 4 + m][nh * 2 + n] = __builtin_amdgcn_mfma_f32_16x16x32_bf16(
              af[m * 2 + kk], bfr[nh * 4 + n * 2 + kk],
              acc[mh * 4 + m][nh * 2 + n], 0, 0, 0);
    __builtin_amdgcn_s_setprio(0);
  };

  // prologue: 7 half-tiles ahead (K0 full + K1 A-h0,B-h0,A-h1)
#pragma unroll
  for (int g = 0; g < 7; ++g) stage(g);
  asm volatile("s_waitcnt vmcnt(6)" ::: "memory");   // K0 resident
  __builtin_amdgcn_s_barrier();

  for (int t2 = 0; t2 < NT; ++t2) {
    const int buf = t2 & 1;
    const int gb  = t2 * 4 + 7;
    // phase 0: quadrant (0,0)
    lda_frag(buf, 0);
    ldb_frag(buf, 0);
    stage(gb + 0);                                   // B-h1(t2+1) -> other buf
    asm volatile("s_waitcnt lgkmcnt(8)" ::: "memory");
    __builtin_amdgcn_s_barrier();
    asm volatile("s_waitcnt lgkmcnt(0)" ::: "memory");
    mma_quad(0, 0);
    __builtin_amdgcn_s_barrier();
    // phase 1: quadrant (0,1)
    ldb_frag(buf, 1);
    stage(gb + 1);                                   // A-h0(t2+2) -> this buf
    __builtin_amdgcn_s_barrier();
    asm volatile("s_waitcnt lgkmcnt(0)" ::: "memory");
    mma_quad(0, 1);
    __builtin_amdgcn_s_barrier();
    // phase 2: quadrant (1,0)
    lda_frag(buf, 1);
    stage(gb + 2);                                   // B-h0(t2+2)
    __builtin_amdgcn_s_barrier();
    asm volatile("s_waitcnt lgkmcnt(0)" ::: "memory");
    mma_quad(1, 0);
    __builtin_amdgcn_s_barrier();
    // phase 3: quadrant (1,1)
    stage(gb + 3);                                   // A-h1(t2+2)
    if (t2 < NT - 2) asm volatile("s_waitcnt vmcnt(6)" ::: "memory");
    else             asm volatile("s_waitcnt vmcnt(0)" ::: "memory");
    __builtin_amdgcn_s_barrier();
    mma_quad(1, 1);
    __builtin_amdgcn_s_barrier();
  }

  // epilogue: bias(t) + ReLU, bf16 out
#pragma unroll
  for (int n = 0; n < 4; ++n) {
    const int gcol = bn + wc * 64 + n * 16 + fr;
    const float bv = bias[gcol] + t * wtime[gcol];
#pragma unroll
    for (int m = 0; m < 8; ++m) {
      const int grow0 = bm + wr * 128 + m * 16 + (fq << 2);
#pragma unroll
      for (int r = 0; r < 4; ++r) {
        float v = acc[m][n][r] + bv;
        v = v > 0.0f ? v : 0.0f;
        C[(size_t)(grow0 + r) * ldc + gcol] = (bf16_t)v;
      }
    }
  }
}

// ---------------------------------------------------------------------------
// Round-1 proven 128^2 kernel — kept for layer 0 (K=64).
// ---------------------------------------------------------------------------
template<int BM, int BN, int BK, int WROWS, int WCOLS, bool RELU, bool OUT_BF16>
__global__ __launch_bounds__(256) void gemm_bt(
    const bf16_t* __restrict__ A, int lda,
    const bf16_t* __restrict__ BT,
    const float* __restrict__ bias,
    const float* __restrict__ wtime,
    float t,
    void* __restrict__ Cv, int ldc,
    int M, int K)
{
  constexpr int MR  = BM / WROWS / 16;
  constexpr int NR  = BN / WCOLS / 16;
  constexpr int TPR = BK / 8;
  constexpr int RPW = 64 / TPR;
  constexpr int RPL = 4 * RPW;
  static_assert(BM % RPL == 0 && BN % RPL == 0, "tile staging mismatch");

  __shared__ bf16_t As[BM][BK];
  __shared__ bf16_t Bs[BN][BK];

  const int tid  = threadIdx.x;
  const int wave = tid >> 6;
  const int lane = tid & 63;
  const int wr = wave / WCOLS;
  const int wc = wave % WCOLS;
  const int bm = blockIdx.x * BM;
  const int bn = blockIdx.y * BN;
  const int lrow = lane / TPR;
  const int lcol = (lane % TPR) * 8;

  f32x4 acc[MR][NR] = {};

  for (int k0 = 0; k0 < K; k0 += BK) {
#pragma unroll
    for (int i = 0; i < BM / RPL; ++i) {
      const int rb = i * RPL + wave * RPW;
      gload_lds16(&A[(size_t)(bm + rb + lrow) * lda + k0 + lcol], &As[rb][0]);
    }
#pragma unroll
    for (int i = 0; i < BN / RPL; ++i) {
      const int rb = i * RPL + wave * RPW;
      gload_lds16(&BT[(size_t)(bn + rb + lrow) * K + k0 + lcol], &Bs[rb][0]);
    }
    __syncthreads();
#pragma unroll
    for (int kk = 0; kk < BK / 32; ++kk) {
      bf16x8 af[MR], bfr[NR];
#pragma unroll
      for (int m = 0; m < MR; ++m)
        af[m] = *(const bf16x8*)&As[wr * (BM / WROWS) + m * 16 + (lane & 15)]
                                  [kk * 32 + (lane >> 4) * 8];
#pragma unroll
      for (int n = 0; n < NR; ++n)
        bfr[n] = *(const bf16x8*)&Bs[wc * (BN / WCOLS) + n * 16 + (lane & 15)]
                                    [kk * 32 + (lane >> 4) * 8];
#pragma unroll
      for (int m = 0; m < MR; ++m)
#pragma unroll
        for (int n = 0; n < NR; ++n)
          acc[m][n] = __builtin_amdgcn_mfma_f32_16x16x32_bf16(
              af[m], bfr[n], acc[m][n], 0, 0, 0);
    }
    __syncthreads();
  }

#pragma unroll
  for (int n = 0; n < NR; ++n) {
    const int gcol = bn + wc * (BN / WCOLS) + n * 16 + (lane & 15);
    const float bv = bias[gcol] + t * wtime[gcol];
#pragma unroll
    for (int m = 0; m < MR; ++m) {
      const int grow0 = bm + wr * (BM / WROWS) + m * 16 + ((lane >> 4) << 2);
#pragma unroll
      for (int r = 0; r < 4; ++r) {
        float v = acc[m][n][r] + bv;
        if (RELU) v = v > 0.0f ? v : 0.0f;
        if constexpr (OUT_BF16)
          ((bf16_t*)Cv)[(size_t)(grow0 + r) * ldc + gcol] = (bf16_t)v;
        else
          ((float*)Cv)[(size_t)(grow0 + r) * ldc + gcol] = v;
      }
    }
  }
}

// ---------------------------------------------------------------------------
// Layer 4 (N=64, K=1024) with RK4 combine fused into the epilogue.
// BM=128, BN=64 -> 256 blocks (full GPU). kv = acc + bias + t*wt (no ReLU).
// mode 0: accb = kv;          ybf = bf16(y + cs*kv)
// mode 1: accb += ca*kv;      ybf = bf16(y + cs*kv)
// mode 2: y += cs*(accb+kv);  ybf = bf16(y)
// ---------------------------------------------------------------------------
__global__ __launch_bounds__(256) void gemm_l4_rk4(
    const bf16_t* __restrict__ A, int lda,
    const bf16_t* __restrict__ BT,
    const float* __restrict__ bias,
    const float* __restrict__ wtime,
    float t,
    float* __restrict__ y, float* __restrict__ accb,
    bf16_t* __restrict__ ybf,
    float ca, float cs, int mode,
    int M, int K)
{
  constexpr int BM = 128, BN = 64, BK = 64;
  constexpr int MR = 4, NR = 2;      // 4 waves: 2x2, per-wave 64x32

  __shared__ bf16_t As[BM][BK];
  __shared__ bf16_t Bs[BN][BK];

  const int tid  = threadIdx.x;
  const int wave = tid >> 6;
  const int lane = tid & 63;
  const int wr = wave >> 1;
  const int wc = wave & 1;
  const int bm = blockIdx.x * BM;
  const int lrow = lane >> 3;
  const int lcol = (lane & 7) * 8;

  f32x4 acc[MR][NR] = {};

  for (int k0 = 0; k0 < K; k0 += BK) {
#pragma unroll
    for (int i = 0; i < 4; ++i) {
      const int rb = i * 32 + wave * 8;
      gload_lds16(&A[(size_t)(bm + rb + lrow) * lda + k0 + lcol], &As[rb][0]);
    }
#pragma unroll
    for (int i = 0; i < 2; ++i) {
      const int rb = i * 32 + wave * 8;
      gload_lds16(&BT[(size_t)(rb + lrow) * K + k0 + lcol], &Bs[rb][0]);
    }
    __syncthreads();
#pragma unroll
    for (int kk = 0; kk < 2; ++kk) {
      bf16x8 af[MR], bfr[NR];
#pragma unroll
      for (int m = 0; m < MR; ++m)
        af[m] = *(const bf16x8*)&As[wr * 64 + m * 16 + (lane & 15)]
                                  [kk * 32 + (lane >> 4) * 8];
#pragma unroll
      for (int n = 0; n < NR; ++n)
        bfr[n] = *(const bf16x8*)&Bs[wc * 32 + n * 16 + (lane & 15)]
                                    [kk * 32 + (lane >> 4) * 8];
#pragma unroll
      for (int m = 0; m < MR; ++m)
#pragma unroll
        for (int n = 0; n < NR; ++n)
          acc[m][n] = __builtin_amdgcn_mfma_f32_16x16x32_bf16(
              af[m], bfr[n], acc[m][n], 0, 0, 0);
    }
    __syncthreads();
  }

#pragma unroll
  for (int n = 0; n < NR; ++n) {
    const int gcol = wc * 32 + n * 16 + (lane & 15);
    const float bv = bias[gcol] + t * wtime[gcol];
#pragma unroll
    for (int m = 0; m < MR; ++m) {
      const int grow0 = bm + wr * 64 + m * 16 + ((lane >> 4) << 2);
#pragma unroll
      for (int r = 0; r < 4; ++r) {
        const float kv = acc[m][n][r] + bv;
        const size_t o = (size_t)(grow0 + r) * 64 + gcol;
        if (mode == 0) {
          accb[o] = kv;
          ybf[o] = (bf16_t)(y[o] + cs * kv);
        } else if (mode == 1) {
          accb[o] += ca * kv;
          ybf[o] = (bf16_t)(y[o] + cs * kv);
        } else {
          const float ny = y[o] + cs * (accb[o] + kv);
          y[o] = ny;
          ybf[o] = (bf16_t)ny;
        }
      }
    }
  }
}

// ---------------------------------------------------------------------------
__global__ void prep_weight(const float* __restrict__ W, const float* __restrict__ b,
                            bf16_t* __restrict__ WT, float* __restrict__ bias,
                            float* __restrict__ wtime,
                            int K, int N, int Kpad, int Npad)
{
  int idx = blockIdx.x * 256 + threadIdx.x;
  int total = Npad * Kpad;
  if (idx < total) {
    int n = idx / Kpad, k = idx % Kpad;
    float v = (n < N && k < K) ? W[(size_t)k * N + n] : 0.0f;
    WT[idx] = (bf16_t)v;
  }
  if (idx < Npad) {
    bias[idx]  = (idx < N) ? b[idx] : 0.0f;
    wtime[idx] = (idx < N) ? W[(size_t)K * N + idx] : 0.0f;
  }
}

__global__ void init_y(const float* __restrict__ x, float* __restrict__ y,
                       bf16_t* __restrict__ ybf, int M)
{
  int i = blockIdx.x * 256 + threadIdx.x;
  if (i < M * 64) {
    int m = i >> 6, c = i & 63;
    float v = (c < 2) ? x[m * 2 + c] : 0.0f;
    y[i] = v;
    ybf[i] = (bf16_t)v;
  }
}

__global__ void extract_out(const float* __restrict__ y, float* __restrict__ out, int M)
{
  int i = blockIdx.x * 256 + threadIdx.x;
  if (i < M * 3) {
    int m = i / 3, c = i % 3;
    out[i] = y[(size_t)m * 64 + c];
  }
}

extern "C" void kernel_launch(void* const* d_in, const int* in_sizes, int n_in,
                              void* d_out, int out_size, void* d_ws, size_t ws_size,
                              hipStream_t stream)
{
  (void)in_sizes; (void)n_in; (void)out_size; (void)ws_size;
  const int M = 32768;

  const float* x = (const float*)d_in[0];
  const float* Wp[5]; const float* bp[5];
  for (int i = 0; i < 5; ++i) {
    Wp[i] = (const float*)d_in[1 + 2 * i];
    bp[i] = (const float*)d_in[2 + 2 * i];
  }

  char* ws = (char*)d_ws; size_t off = 0;
  auto alloc = [&](size_t bytes) -> char* {
    char* p = ws + off; off += (bytes + 255) & ~(size_t)255; return p;
  };

  bf16_t* WT[5];
  WT[0] = (bf16_t*)alloc((size_t)1024 * 64 * 2);
  WT[1] = (bf16_t*)alloc((size_t)1024 * 1024 * 2);
  WT[2] = (bf16_t*)alloc((size_t)1024 * 1024 * 2);
  WT[3] = (bf16_t*)alloc((size_t)1024 * 1024 * 2);
  WT[4] = (bf16_t*)alloc((size_t)64 * 1024 * 2);
  float* bias[5]; float* wtm[5];
  for (int i = 0; i < 5; ++i) {
    int Np = (i == 4) ? 64 : 1024;
    bias[i] = (float*)alloc((size_t)Np * 4);
    wtm[i]  = (float*)alloc((size_t)Np * 4);
  }
  float*  y    = (float*)alloc((size_t)M * 64 * 4);
  float*  accb = (float*)alloc((size_t)M * 64 * 4);
  bf16_t* ybf  = (bf16_t*)alloc((size_t)M * 64 * 2);
  bf16_t* act0 = (bf16_t*)alloc((size_t)M * 1024 * 2);
  bf16_t* act1 = (bf16_t*)alloc((size_t)M * 1024 * 2);

  const int Kd[5]  = {50, 1024, 1024, 1024, 1024};
  const int Nd[5]  = {1024, 1024, 1024, 1024, 50};
  const int Kpd[5] = {64, 1024, 1024, 1024, 1024};
  const int Npd[5] = {1024, 1024, 1024, 1024, 64};
  for (int i = 0; i < 5; ++i) {
    int tot = Npd[i] * Kpd[i];
    prep_weight<<<dim3((tot + 255) / 256), 256, 0, stream>>>(
        Wp[i], bp[i], WT[i], bias[i], wtm[i], Kd[i], Nd[i], Kpd[i], Npd[i]);
  }

  init_y<<<dim3((M * 64 + 255) / 256), 256, 0, stream>>>(x, y, ybf, M);

  const float dtv = 1.0f / 32.0f;
  dim3 gL0(M / 128, 1024 / 128);        // 256 x 8
  dim3 g256(M / 256 * (1024 / 256));    // 512 blocks, %8 == 0
  dim3 gL4(M / 128);                    // 256 blocks

  auto run_net = [&](float t, float ca, float cs, int mode) {
    gemm_bt<128,128,64,2,2,true,true><<<gL0, 256, 0, stream>>>(
        ybf, 64, WT[0], bias[0], wtm[0], t, act0, 1024, M, 64);
    gemm256<1024><<<g256, 512, 0, stream>>>(
        act0, WT[1], bias[1], wtm[1], t, act1, 1024, M, 1024);
    gemm256<1024><<<g256, 512, 0, stream>>>(
        act1, WT[2], bias[2], wtm[2], t, act0, 1024, M, 1024);
    gemm256<1024><<<g256, 512, 0, stream>>>(
        act0, WT[3], bias[3], wtm[3], t, act1, 1024, M, 1024);
    gemm_l4_rk4<<<gL4, 256, 0, stream>>>(
        act1, 1024, WT[4], bias[4], wtm[4], t,
        y, accb, ybf, ca, cs, mode, M, 1024);
  };

  for (int i = 0; i < 32; ++i) {
    const float t0 = i * dtv;
    const float tm = t0 + 0.5f * dtv;
    const float t1 = t0 + dtv;
    run_net(t0, 0.0f, 0.5f * dtv, 0);   // k1
    run_net(tm, 2.0f, 0.5f * dtv, 1);   // k2
    run_net(tm, 2.0f, dtv,        1);   // k3
    run_net(t1, 0.0f, dtv / 6.0f, 2);   // k4
  }

  extract_out<<<dim3((M * 3 + 255) / 256), 256, 0, stream>>>(y, (float*)d_out, M);
}

// Round 3
// 39596.002 us; speedup vs baseline: 1.2577x; 1.0340x over previous
//
#include <hip/hip_runtime.h>
#include <hip/hip_bf16.h>
#include <stdint.h>

// Neural ODE (RK4, 32 steps) over a 5-layer MLP, B=32768, VAR_DIM=50 (pad 64).
// bf16 MFMA GEMMs (16x16x32), fp32 accum, fp32 state y.
// concat(h,t) @ W == h @ W[:K] + (b + t*W[K]) -> time column folded into bias.
// Layers 1-3: 256^2/8-wave/8-phase pipelined GEMM (T1+T2+T3+T4+T5).
//   Stage order fixed (r3): every LDS write lands >=1 phase after the
//   region's last ds_read (A last-read ph2, B last-read ph1).
// Layer 4 (N=64): 64x64 GEMM + RK4 combine fused; 512 blocks = 2/CU.

typedef __bf16 bf16_t;
typedef bf16_t bf16x8 __attribute__((ext_vector_type(8)));
typedef float  f32x4  __attribute__((ext_vector_type(4)));

#define DEVI static __device__ __forceinline__

DEVI void gload_lds16(const bf16_t* gsrc, bf16_t* ldst) {
  __builtin_amdgcn_global_load_lds(
      (const __attribute__((address_space(1))) uint32_t*)gsrc,
      (__attribute__((address_space(3))) uint32_t*)ldst,
      16, 0, 0);
}

// ---------------------------------------------------------------------------
// 256x256 tile, BK=64, 8 waves (2Mx4N), double-buffered LDS, 8-phase schedule.
// st_16x32 LDS swizzle via pre-swizzled global source + same XOR on ds_read.
// vmcnt(4) once per K-tile (2 half-tiles in flight); drain only in tail.
// ---------------------------------------------------------------------------
template<int K>
__global__ __launch_bounds__(512, 2) void gemm256(
    const bf16_t* __restrict__ A,     // M x K row-major
    const bf16_t* __restrict__ BT,    // N x K row-major (pre-transposed W)
    const float* __restrict__ bias,
    const float* __restrict__ wtime,
    float t,
    bf16_t* __restrict__ C, int ldc,
    int M, int N)
{
  constexpr int NT = K / 64;          // K-tiles
  static_assert(NT >= 2, "need >=2 K-tiles");

  __shared__ __align__(16) bf16_t As[2][256][64];
  __shared__ __align__(16) bf16_t Bs[2][256][64];

  const int tid  = threadIdx.x;
  const int wave = tid >> 6;
  const int lane = tid & 63;
  const int wr = wave >> 2;           // 0..1 -> 128-row half
  const int wc = wave & 3;            // 0..3 -> 64-col strip

  // T1: XCD-aware bijective swizzle (gridDim.x % 8 == 0 by construction)
  int wg = blockIdx.x;
  {
    const int cpx = gridDim.x >> 3;
    wg = (wg & 7) * cpx + (wg >> 3);
  }
  const int nbn = N >> 8;
  const int bm = (wg / nbn) << 8;
  const int bn = (wg % nbn) << 8;

  // staging: each wave covers 8 rows per load instr; pre-swizzled source col
  const int srow = lane >> 3;
  const int scol = ((lane & 7) << 3) ^ ((lane & 32) >> 1);
  const bf16_t* aS = A  + (size_t)(bm + wave * 8 + srow) * K + scol;
  const bf16_t* bS = BT + (size_t)(bn + wave * 8 + srow) * K + scol;
  bf16_t* aD = &As[0][0][0] + wave * 8 * 64;   // wave-uniform LDS base
  bf16_t* bD = &Bs[0][0][0] + wave * 8 * 64;

  // stage one half-tile (128 rows x 64 cols) = 2 load instrs
  auto stageHalf = [&](int kt, int isB, int h) {
    const int buf = kt & 1;
    const bf16_t* src = (isB ? bS : aS) + (size_t)(h * 128) * K + kt * 64;
    bf16_t*       dst = (isB ? bD : aD) + (buf * 256 + h * 128) * 64;
    gload_lds16(src,                 dst);
    gload_lds16(src + (size_t)64 * K, dst + 64 * 64);
  };

  const int fr = lane & 15;
  const int fq = lane >> 4;

  bf16x8 af[8];        // A quadrant frags [m*2+kk]
  bf16x8 bfr[8];       // B frags [nh*4 + n*2 + kk]
  f32x4  acc[8][4] = {};

  auto lda_frag = [&](int buf, int mh) {
    const char* base = (const char*)&As[buf][0][0];
#pragma unroll
    for (int m = 0; m < 4; ++m)
#pragma unroll
      for (int kk = 0; kk < 2; ++kk) {
        int r  = wr * 128 + (mh * 4 + m) * 16 + fr;
        int cb = (kk * 64 + fq * 16) ^ ((r & 4) << 3);
        af[m * 2 + kk] = *(const bf16x8*)(base + r * 128 + cb);
      }
  };
  auto ldb_frag = [&](int buf, int nh) {
    const char* base = (const char*)&Bs[buf][0][0];
#pragma unroll
    for (int n = 0; n < 2; ++n)
#pragma unroll
      for (int kk = 0; kk < 2; ++kk) {
        int r  = wc * 64 + (nh * 2 + n) * 16 + fr;
        int cb = (kk * 64 + fq * 16) ^ ((r & 4) << 3);
        bfr[nh * 4 + n * 2 + kk] = *(const bf16x8*)(base + r * 128 + cb);
      }
  };
  auto mma_quad = [&](int mh, int nh) {
    __builtin_amdgcn_s_setprio(1);
#pragma unroll
    for (int m = 0; m < 4; ++m)
#pragma unroll
      for (int n = 0; n < 2; ++n)
#pragma unroll
        for (int kk = 0; kk < 2; ++kk)
          acc[mh * 4 + m][nh * 2 + n] = __builtin_amdgcn_mfma_f32_16x16x32_bf16(
              af[m * 2 + kk], bfr[nh * 4 + n * 2 + kk],
              acc[mh * 4 + m][nh * 2 + n], 0, 0, 0);
    __builtin_amdgcn_s_setprio(0);
  };

  // prologue: tile0 full + tile1 {Bh0, Ah0}  (matches steady-state p2/p3 order)
  stageHalf(0, 0, 0); stageHalf(0, 1, 0);
  stageHalf(0, 0, 1); stageHalf(0, 1, 1);
  stageHalf(1, 1, 0); stageHalf(1, 0, 0);
  asm volatile("s_waitcnt vmcnt(4)" ::: "memory");   // tile0 resident
  __builtin_amdgcn_s_barrier();

  for (int t2 = 0; t2 < NT; ++t2) {
    const int buf = t2 & 1;
    // phase 0: quadrant (0,0); stage Ah1(t2+1) -> other buf
    lda_frag(buf, 0);
    ldb_frag(buf, 0);
    if (t2 + 1 < NT) stageHalf(t2 + 1, 0, 1);
    asm volatile("s_waitcnt lgkmcnt(8)" ::: "memory");
    __builtin_amdgcn_s_barrier();
    asm volatile("s_waitcnt lgkmcnt(0)" ::: "memory");
    mma_quad(0, 0);
    __builtin_amdgcn_s_barrier();
    // phase 1: quadrant (0,1); stage Bh1(t2+1) -> other buf
    ldb_frag(buf, 1);
    if (t2 + 1 < NT) stageHalf(t2 + 1, 1, 1);
    __builtin_amdgcn_s_barrier();
    asm volatile("s_waitcnt lgkmcnt(0)" ::: "memory");
    mma_quad(0, 1);
    __builtin_amdgcn_s_barrier();
    // phase 2: quadrant (1,0); stage Bh0(t2+2) -> current buf (B last read p1)
    lda_frag(buf, 1);
    if (t2 + 2 < NT) stageHalf(t2 + 2, 1, 0);
    __builtin_amdgcn_s_barrier();
    asm volatile("s_waitcnt lgkmcnt(0)" ::: "memory");
    mma_quad(1, 0);
    __builtin_amdgcn_s_barrier();
    // phase 3: quadrant (1,1); stage Ah0(t2+2) -> current buf (A last read p2)
    if (t2 + 2 < NT) {
      stageHalf(t2 + 2, 0, 0);
      asm volatile("s_waitcnt vmcnt(4)" ::: "memory");  // tile t2+1 resident
    } else {
      asm volatile("s_waitcnt vmcnt(0)" ::: "memory");
    }
    __builtin_amdgcn_s_barrier();
    mma_quad(1, 1);
    __builtin_amdgcn_s_barrier();
  }

  // epilogue: bias(t) + ReLU, bf16 out
#pragma unroll
  for (int n = 0; n < 4; ++n) {
    const int gcol = bn + wc * 64 + n * 16 + fr;
    const float bv = bias[gcol] + t * wtime[gcol];
#pragma unroll
    for (int m = 0; m < 8; ++m) {
      const int grow0 = bm + wr * 128 + m * 16 + (fq << 2);
#pragma unroll
      for (int r = 0; r < 4; ++r) {
        float v = acc[m][n][r] + bv;
        v = v > 0.0f ? v : 0.0f;
        C[(size_t)(grow0 + r) * ldc + gcol] = (bf16_t)v;
      }
    }
  }
}

// ---------------------------------------------------------------------------
// Round-1 proven 128^2 kernel — kept for layer 0 (K=64).
// ---------------------------------------------------------------------------
template<int BM, int BN, int BK, int WROWS, int WCOLS, bool RELU, bool OUT_BF16>
__global__ __launch_bounds__(256) void gemm_bt(
    const bf16_t* __restrict__ A, int lda,
    const bf16_t* __restrict__ BT,
    const float* __restrict__ bias,
    const float* __restrict__ wtime,
    float t,
    void* __restrict__ Cv, int ldc,
    int M, int K)
{
  constexpr int MR  = BM / WROWS / 16;
  constexpr int NR  = BN / WCOLS / 16;
  constexpr int TPR = BK / 8;
  constexpr int RPW = 64 / TPR;
  constexpr int RPL = 4 * RPW;
  static_assert(BM % RPL == 0 && BN % RPL == 0, "tile staging mismatch");

  __shared__ bf16_t As[BM][BK];
  __shared__ bf16_t Bs[BN][BK];

  const int tid  = threadIdx.x;
  const int wave = tid >> 6;
  const int lane = tid & 63;
  const int wr = wave / WCOLS;
  const int wc = wave % WCOLS;
  const int bm = blockIdx.x * BM;
  const int bn = blockIdx.y * BN;
  const int lrow = lane / TPR;
  const int lcol = (lane % TPR) * 8;

  f32x4 acc[MR][NR] = {};

  for (int k0 = 0; k0 < K; k0 += BK) {
#pragma unroll
    for (int i = 0; i < BM / RPL; ++i) {
      const int rb = i * RPL + wave * RPW;
      gload_lds16(&A[(size_t)(bm + rb + lrow) * lda + k0 + lcol], &As[rb][0]);
    }
#pragma unroll
    for (int i = 0; i < BN / RPL; ++i) {
      const int rb = i * RPL + wave * RPW;
      gload_lds16(&BT[(size_t)(bn + rb + lrow) * K + k0 + lcol], &Bs[rb][0]);
    }
    __syncthreads();
#pragma unroll
    for (int kk = 0; kk < BK / 32; ++kk) {
      bf16x8 af[MR], bfr[NR];
#pragma unroll
      for (int m = 0; m < MR; ++m)
        af[m] = *(const bf16x8*)&As[wr * (BM / WROWS) + m * 16 + (lane & 15)]
                                  [kk * 32 + (lane >> 4) * 8];
#pragma unroll
      for (int n = 0; n < NR; ++n)
        bfr[n] = *(const bf16x8*)&Bs[wc * (BN / WCOLS) + n * 16 + (lane & 15)]
                                    [kk * 32 + (lane >> 4) * 8];
#pragma unroll
      for (int m = 0; m < MR; ++m)
#pragma unroll
        for (int n = 0; n < NR; ++n)
          acc[m][n] = __builtin_amdgcn_mfma_f32_16x16x32_bf16(
              af[m], bfr[n], acc[m][n], 0, 0, 0);
    }
    __syncthreads();
  }

#pragma unroll
  for (int n = 0; n < NR; ++n) {
    const int gcol = bn + wc * (BN / WCOLS) + n * 16 + (lane & 15);
    const float bv = bias[gcol] + t * wtime[gcol];
#pragma unroll
    for (int m = 0; m < MR; ++m) {
      const int grow0 = bm + wr * (BM / WROWS) + m * 16 + ((lane >> 4) << 2);
#pragma unroll
      for (int r = 0; r < 4; ++r) {
        float v = acc[m][n][r] + bv;
        if (RELU) v = v > 0.0f ? v : 0.0f;
        if constexpr (OUT_BF16)
          ((bf16_t*)Cv)[(size_t)(grow0 + r) * ldc + gcol] = (bf16_t)v;
        else
          ((float*)Cv)[(size_t)(grow0 + r) * ldc + gcol] = v;
      }
    }
  }
}

// ---------------------------------------------------------------------------
// Layer 4 (N=64, K=1024) with RK4 combine fused into the epilogue.
// BM=64, BN=64, 4 waves (2x2, per-wave 32x32) -> 512 blocks = 2 blocks/CU.
// kv = acc + bias + t*wt (no ReLU).
// mode 0: accb = kv;          ybf = bf16(y + cs*kv)
// mode 1: accb += ca*kv;      ybf = bf16(y + cs*kv)
// mode 2: y += cs*(accb+kv);  ybf = bf16(y)
// ---------------------------------------------------------------------------
__global__ __launch_bounds__(256) void gemm_l4_rk4(
    const bf16_t* __restrict__ A, int lda,
    const bf16_t* __restrict__ BT,
    const float* __restrict__ bias,
    const float* __restrict__ wtime,
    float t,
    float* __restrict__ y, float* __restrict__ accb,
    bf16_t* __restrict__ ybf,
    float ca, float cs, int mode,
    int M, int K)
{
  constexpr int BM = 64, BN = 64, BK = 64;
  constexpr int MR = 2, NR = 2;

  __shared__ bf16_t As[BM][BK];
  __shared__ bf16_t Bs[BN][BK];

  const int tid  = threadIdx.x;
  const int wave = tid >> 6;
  const int lane = tid & 63;
  const int wr = wave >> 1;
  const int wc = wave & 1;
  const int bm = blockIdx.x * BM;
  const int lrow = lane >> 3;
  const int lcol = (lane & 7) * 8;

  f32x4 acc[MR][NR] = {};

  for (int k0 = 0; k0 < K; k0 += BK) {
#pragma unroll
    for (int i = 0; i < 2; ++i) {
      const int rb = i * 32 + wave * 8;
      gload_lds16(&A[(size_t)(bm + rb + lrow) * lda + k0 + lcol], &As[rb][0]);
    }
#pragma unroll
    for (int i = 0; i < 2; ++i) {
      const int rb = i * 32 + wave * 8;
      gload_lds16(&BT[(size_t)(rb + lrow) * K + k0 + lcol], &Bs[rb][0]);
    }
    __syncthreads();
#pragma unroll
    for (int kk = 0; kk < 2; ++kk) {
      bf16x8 af[MR], bfr[NR];
#pragma unroll
      for (int m = 0; m < MR; ++m)
        af[m] = *(const bf16x8*)&As[wr * 32 + m * 16 + (lane & 15)]
                                  [kk * 32 + (lane >> 4) * 8];
#pragma unroll
      for (int n = 0; n < NR; ++n)
        bfr[n] = *(const bf16x8*)&Bs[wc * 32 + n * 16 + (lane & 15)]
                                    [kk * 32 + (lane >> 4) * 8];
#pragma unroll
      for (int m = 0; m < MR; ++m)
#pragma unroll
        for (int n = 0; n < NR; ++n)
          acc[m][n] = __builtin_amdgcn_mfma_f32_16x16x32_bf16(
              af[m], bfr[n], acc[m][n], 0, 0, 0);
    }
    __syncthreads();
  }

#pragma unroll
  for (int n = 0; n < NR; ++n) {
    const int gcol = wc * 32 + n * 16 + (lane & 15);
    const float bv = bias[gcol] + t * wtime[gcol];
#pragma unroll
    for (int m = 0; m < MR; ++m) {
      const int grow0 = bm + wr * 32 + m * 16 + ((lane >> 4) << 2);
#pragma unroll
      for (int r = 0; r < 4; ++r) {
        const float kv = acc[m][n][r] + bv;
        const size_t o = (size_t)(grow0 + r) * 64 + gcol;
        if (mode == 0) {
          accb[o] = kv;
          ybf[o] = (bf16_t)(y[o] + cs * kv);
        } else if (mode == 1) {
          accb[o] += ca * kv;
          ybf[o] = (bf16_t)(y[o] + cs * kv);
        } else {
          const float ny = y[o] + cs * (accb[o] + kv);
          y[o] = ny;
          ybf[o] = (bf16_t)ny;
        }
      }
    }
  }
}

// ---------------------------------------------------------------------------
__global__ void prep_weight(const float* __restrict__ W, const float* __restrict__ b,
                            bf16_t* __restrict__ WT, float* __restrict__ bias,
                            float* __restrict__ wtime,
                            int K, int N, int Kpad, int Npad)
{
  int idx = blockIdx.x * 256 + threadIdx.x;
  int total = Npad * Kpad;
  if (idx < total) {
    int n = idx / Kpad, k = idx % Kpad;
    float v = (n < N && k < K) ? W[(size_t)k * N + n] : 0.0f;
    WT[idx] = (bf16_t)v;
  }
  if (idx < Npad) {
    bias[idx]  = (idx < N) ? b[idx] : 0.0f;
    wtime[idx] = (idx < N) ? W[(size_t)K * N + idx] : 0.0f;
  }
}

__global__ void init_y(const float* __restrict__ x, float* __restrict__ y,
                       bf16_t* __restrict__ ybf, int M)
{
  int i = blockIdx.x * 256 + threadIdx.x;
  if (i < M * 64) {
    int m = i >> 6, c = i & 63;
    float v = (c < 2) ? x[m * 2 + c] : 0.0f;
    y[i] = v;
    ybf[i] = (bf16_t)v;
  }
}

__global__ void extract_out(const float* __restrict__ y, float* __restrict__ out, int M)
{
  int i = blockIdx.x * 256 + threadIdx.x;
  if (i < M * 3) {
    int m = i / 3, c = i % 3;
    out[i] = y[(size_t)m * 64 + c];
  }
}

extern "C" void kernel_launch(void* const* d_in, const int* in_sizes, int n_in,
                              void* d_out, int out_size, void* d_ws, size_t ws_size,
                              hipStream_t stream)
{
  (void)in_sizes; (void)n_in; (void)out_size; (void)ws_size;
  const int M = 32768;

  const float* x = (const float*)d_in[0];
  const float* Wp[5]; const float* bp[5];
  for (int i = 0; i < 5; ++i) {
    Wp[i] = (const float*)d_in[1 + 2 * i];
    bp[i] = (const float*)d_in[2 + 2 * i];
  }

  char* ws = (char*)d_ws; size_t off = 0;
  auto alloc = [&](size_t bytes) -> char* {
    char* p = ws + off; off += (bytes + 255) & ~(size_t)255; return p;
  };

  bf16_t* WT[5];
  WT[0] = (bf16_t*)alloc((size_t)1024 * 64 * 2);
  WT[1] = (bf16_t*)alloc((size_t)1024 * 1024 * 2);
  WT[2] = (bf16_t*)alloc((size_t)1024 * 1024 * 2);
  WT[3] = (bf16_t*)alloc((size_t)1024 * 1024 * 2);
  WT[4] = (bf16_t*)alloc((size_t)64 * 1024 * 2);
  float* bias[5]; float* wtm[5];
  for (int i = 0; i < 5; ++i) {
    int Np = (i == 4) ? 64 : 1024;
    bias[i] = (float*)alloc((size_t)Np * 4);
    wtm[i]  = (float*)alloc((size_t)Np * 4);
  }
  float*  y    = (float*)alloc((size_t)M * 64 * 4);
  float*  accb = (float*)alloc((size_t)M * 64 * 4);
  bf16_t* ybf  = (bf16_t*)alloc((size_t)M * 64 * 2);
  bf16_t* act0 = (bf16_t*)alloc((size_t)M * 1024 * 2);
  bf16_t* act1 = (bf16_t*)alloc((size_t)M * 1024 * 2);

  const int Kd[5]  = {50, 1024, 1024, 1024, 1024};
  const int Nd[5]  = {1024, 1024, 1024, 1024, 50};
  const int Kpd[5] = {64, 1024, 1024, 1024, 1024};
  const int Npd[5] = {1024, 1024, 1024, 1024, 64};
  for (int i = 0; i < 5; ++i) {
    int tot = Npd[i] * Kpd[i];
    prep_weight<<<dim3((tot + 255) / 256), 256, 0, stream>>>(
        Wp[i], bp[i], WT[i], bias[i], wtm[i], Kd[i], Nd[i], Kpd[i], Npd[i]);
  }

  init_y<<<dim3((M * 64 + 255) / 256), 256, 0, stream>>>(x, y, ybf, M);

  const float dtv = 1.0f / 32.0f;
  dim3 gL0(M / 128, 1024 / 128);        // 2048 blocks
  dim3 g256(M / 256 * (1024 / 256));    // 512 blocks, %8 == 0
  dim3 gL4(M / 64);                     // 512 blocks = 2/CU

  auto run_net = [&](float t, float ca, float cs, int mode) {
    gemm_bt<128,128,64,2,2,true,true><<<gL0, 256, 0, stream>>>(
        ybf, 64, WT[0], bias[0], wtm[0], t, act0, 1024, M, 64);
    gemm256<1024><<<g256, 512, 0, stream>>>(
        act0, WT[1], bias[1], wtm[1], t, act1, 1024, M, 1024);
    gemm256<1024><<<g256, 512, 0, stream>>>(
        act1, WT[2], bias[2], wtm[2], t, act0, 1024, M, 1024);
    gemm256<1024><<<g256, 512, 0, stream>>>(
        act0, WT[3], bias[3], wtm[3], t, act1, 1024, M, 1024);
    gemm_l4_rk4<<<gL4, 256, 0, stream>>>(
        act1, 1024, WT[4], bias[4], wtm[4], t,
        y, accb, ybf, ca, cs, mode, M, 1024);
  };

  for (int i = 0; i < 32; ++i) {
    const float t0 = i * dtv;
    const float tm = t0 + 0.5f * dtv;
    const float t1 = t0 + dtv;
    run_net(t0, 0.0f, 0.5f * dtv, 0);   // k1
    run_net(tm, 2.0f, 0.5f * dtv, 1);   // k2
    run_net(tm, 2.0f, dtv,        1);   // k3
    run_net(t1, 0.0f, dtv / 6.0f, 2);   // k4
  }

  extract_out<<<dim3((M * 3 + 255) / 256), 256, 0, stream>>>(y, (float*)d_out, M);
}

// Round 4
// 39381.644 us; speedup vs baseline: 1.2645x; 1.0054x over previous
//
#include <hip/hip_runtime.h>
#include <hip/hip_bf16.h>
#include <stdint.h>

// Neural ODE (RK4, 32 steps) over a 5-layer MLP, B=32768, VAR_DIM=50 (pad 64).
// bf16 MFMA GEMMs (16x16x32), fp32 accum, fp32 state y.
// concat(h,t) @ W == h @ W[:K] + (b + t*W[K]) -> time column folded into bias.
// r4: full bank-spread LDS swizzle (byte bit5 ^= row&4, bit6 ^= row&8) on all
//     GEMM kernels -- previous bit5-only swizzle left 16 claims/bank (2x floor).

typedef __bf16 bf16_t;
typedef bf16_t bf16x8 __attribute__((ext_vector_type(8)));
typedef float  f32x4  __attribute__((ext_vector_type(4)));

#define DEVI static __device__ __forceinline__

DEVI void gload_lds16(const bf16_t* gsrc, bf16_t* ldst) {
  __builtin_amdgcn_global_load_lds(
      (const __attribute__((address_space(1))) uint32_t*)gsrc,
      (__attribute__((address_space(3))) uint32_t*)ldst,
      16, 0, 0);
}

// ---------------------------------------------------------------------------
// 256x256 tile, BK=64, 8 waves (2Mx4N), double-buffered LDS, 8-phase schedule.
// LDS swizzle: physical_col_byte = logical ^ 32*(row&4?1:0) ^ 64*(row&8?1:0).
// Staged via linear global_load_lds dest + pre-swizzled global SOURCE col;
// read with the same XOR on the ds_read byte address.
// vmcnt(4) once per K-tile (2 half-tiles in flight); drain only in tail.
// ---------------------------------------------------------------------------
template<int K>
__global__ __launch_bounds__(512, 2) void gemm256(
    const bf16_t* __restrict__ A,     // M x K row-major
    const bf16_t* __restrict__ BT,    // N x K row-major (pre-transposed W)
    const float* __restrict__ bias,
    const float* __restrict__ wtime,
    float t,
    bf16_t* __restrict__ C, int ldc,
    int M, int N)
{
  constexpr int NT = K / 64;          // K-tiles
  static_assert(NT >= 2, "need >=2 K-tiles");

  __shared__ __align__(16) bf16_t As[2][256][64];
  __shared__ __align__(16) bf16_t Bs[2][256][64];

  const int tid  = threadIdx.x;
  const int wave = tid >> 6;
  const int lane = tid & 63;
  const int wr = wave >> 2;           // 0..1 -> 128-row half
  const int wc = wave & 3;            // 0..3 -> 64-col strip

  // T1: XCD-aware bijective swizzle (gridDim.x % 8 == 0 by construction)
  int wg = blockIdx.x;
  {
    const int cpx = gridDim.x >> 3;
    wg = (wg & 7) * cpx + (wg >> 3);
  }
  const int nbn = N >> 8;
  const int bm = (wg / nbn) << 8;
  const int bn = (wg % nbn) << 8;

  // staging: dest row r = [buf*256 + h*128 +] wave*8 + (lane>>3)
  //   -> r&4 = lane&32-bit, r&8 = wave&1.  Pre-swizzle the SOURCE col:
  //   elem ^= ((lane&32)>>1)  (byte bit5)  ^ ((wave&1)<<5)  (byte bit6)
  const int srow = lane >> 3;
  const int scol = ((lane & 7) << 3) ^ ((lane & 32) >> 1) ^ ((wave & 1) << 5);
  const bf16_t* aS = A  + (size_t)(bm + wave * 8 + srow) * K + scol;
  const bf16_t* bS = BT + (size_t)(bn + wave * 8 + srow) * K + scol;
  bf16_t* aD = &As[0][0][0] + wave * 8 * 64;   // wave-uniform LDS base
  bf16_t* bD = &Bs[0][0][0] + wave * 8 * 64;

  // stage one half-tile (128 rows x 64 cols) = 2 load instrs
  auto stageHalf = [&](int kt, int isB, int h) {
    const int buf = kt & 1;
    const bf16_t* src = (isB ? bS : aS) + (size_t)(h * 128) * K + kt * 64;
    bf16_t*       dst = (isB ? bD : aD) + (buf * 256 + h * 128) * 64;
    gload_lds16(src,                 dst);
    gload_lds16(src + (size_t)64 * K, dst + 64 * 64);
  };

  const int fr = lane & 15;
  const int fq = lane >> 4;
  const int rsw = ((fr & 4) << 3) ^ ((fr & 8) << 3);   // byte-XOR from row bits

  bf16x8 af[8];        // A quadrant frags [m*2+kk]
  bf16x8 bfr[8];       // B frags [nh*4 + n*2 + kk]
  f32x4  acc[8][4] = {};

  auto lda_frag = [&](int buf, int mh) {
    const char* base = (const char*)&As[buf][0][0];
#pragma unroll
    for (int m = 0; m < 4; ++m)
#pragma unroll
      for (int kk = 0; kk < 2; ++kk) {
        int r  = wr * 128 + (mh * 4 + m) * 16 + fr;
        int cb = (kk * 64 + fq * 16) ^ rsw;
        af[m * 2 + kk] = *(const bf16x8*)(base + r * 128 + cb);
      }
  };
  auto ldb_frag = [&](int buf, int nh) {
    const char* base = (const char*)&Bs[buf][0][0];
#pragma unroll
    for (int n = 0; n < 2; ++n)
#pragma unroll
      for (int kk = 0; kk < 2; ++kk) {
        int r  = wc * 64 + (nh * 2 + n) * 16 + fr;
        int cb = (kk * 64 + fq * 16) ^ rsw;
        bfr[nh * 4 + n * 2 + kk] = *(const bf16x8*)(base + r * 128 + cb);
      }
  };
  auto mma_quad = [&](int mh, int nh) {
    __builtin_amdgcn_s_setprio(1);
#pragma unroll
    for (int m = 0; m < 4; ++m)
#pragma unroll
      for (int n = 0; n < 2; ++n)
#pragma unroll
        for (int kk = 0; kk < 2; ++kk)
          acc[mh * 4 + m][nh * 2 + n] = __builtin_amdgcn_mfma_f32_16x16x32_bf16(
              af[m * 2 + kk], bfr[nh * 4 + n * 2 + kk],
              acc[mh * 4 + m][nh * 2 + n], 0, 0, 0);
    __builtin_amdgcn_s_setprio(0);
  };

  // prologue: tile0 full + tile1 {Bh0, Ah0}  (matches steady-state p2/p3 order)
  stageHalf(0, 0, 0); stageHalf(0, 1, 0);
  stageHalf(0, 0, 1); stageHalf(0, 1, 1);
  stageHalf(1, 1, 0); stageHalf(1, 0, 0);
  asm volatile("s_waitcnt vmcnt(4)" ::: "memory");   // tile0 resident
  __builtin_amdgcn_s_barrier();

  for (int t2 = 0; t2 < NT; ++t2) {
    const int buf = t2 & 1;
    // phase 0: quadrant (0,0); stage Ah1(t2+1) -> other buf
    lda_frag(buf, 0);
    ldb_frag(buf, 0);
    if (t2 + 1 < NT) stageHalf(t2 + 1, 0, 1);
    asm volatile("s_waitcnt lgkmcnt(8)" ::: "memory");
    __builtin_amdgcn_s_barrier();
    asm volatile("s_waitcnt lgkmcnt(0)" ::: "memory");
    mma_quad(0, 0);
    __builtin_amdgcn_s_barrier();
    // phase 1: quadrant (0,1); stage Bh1(t2+1) -> other buf
    ldb_frag(buf, 1);
    if (t2 + 1 < NT) stageHalf(t2 + 1, 1, 1);
    __builtin_amdgcn_s_barrier();
    asm volatile("s_waitcnt lgkmcnt(0)" ::: "memory");
    mma_quad(0, 1);
    __builtin_amdgcn_s_barrier();
    // phase 2: quadrant (1,0); stage Bh0(t2+2) -> current buf (B last read p1)
    lda_frag(buf, 1);
    if (t2 + 2 < NT) stageHalf(t2 + 2, 1, 0);
    __builtin_amdgcn_s_barrier();
    asm volatile("s_waitcnt lgkmcnt(0)" ::: "memory");
    mma_quad(1, 0);
    __builtin_amdgcn_s_barrier();
    // phase 3: quadrant (1,1); stage Ah0(t2+2) -> current buf (A last read p2)
    if (t2 + 2 < NT) {
      stageHalf(t2 + 2, 0, 0);
      asm volatile("s_waitcnt vmcnt(4)" ::: "memory");  // tile t2+1 resident
    } else {
      asm volatile("s_waitcnt vmcnt(0)" ::: "memory");
    }
    __builtin_amdgcn_s_barrier();
    mma_quad(1, 1);
    __builtin_amdgcn_s_barrier();
  }

  // epilogue: bias(t) + ReLU, bf16 out
#pragma unroll
  for (int n = 0; n < 4; ++n) {
    const int gcol = bn + wc * 64 + n * 16 + fr;
    const float bv = bias[gcol] + t * wtime[gcol];
#pragma unroll
    for (int m = 0; m < 8; ++m) {
      const int grow0 = bm + wr * 128 + m * 16 + (fq << 2);
#pragma unroll
      for (int r = 0; r < 4; ++r) {
        float v = acc[m][n][r] + bv;
        v = v > 0.0f ? v : 0.0f;
        C[(size_t)(grow0 + r) * ldc + gcol] = (bf16_t)v;
      }
    }
  }
}

// ---------------------------------------------------------------------------
// 128^2 kernel for layer 0 (K=64), now with the full bank-spread swizzle.
// ---------------------------------------------------------------------------
template<int BM, int BN, int BK, int WROWS, int WCOLS, bool RELU, bool OUT_BF16>
__global__ __launch_bounds__(256) void gemm_bt(
    const bf16_t* __restrict__ A, int lda,
    const bf16_t* __restrict__ BT,
    const float* __restrict__ bias,
    const float* __restrict__ wtime,
    float t,
    void* __restrict__ Cv, int ldc,
    int M, int K)
{
  static_assert(BK == 64, "swizzle assumes BK=64");
  constexpr int MR  = BM / WROWS / 16;
  constexpr int NR  = BN / WCOLS / 16;
  constexpr int TPR = BK / 8;        // 8
  constexpr int RPW = 64 / TPR;      // 8
  constexpr int RPL = 4 * RPW;       // 32
  static_assert(BM % RPL == 0 && BN % RPL == 0, "tile staging mismatch");

  __shared__ bf16_t As[BM][BK];
  __shared__ bf16_t Bs[BN][BK];

  const int tid  = threadIdx.x;
  const int wave = tid >> 6;
  const int lane = tid & 63;
  const int wr = wave / WCOLS;
  const int wc = wave % WCOLS;
  const int bm = blockIdx.x * BM;
  const int bn = blockIdx.y * BN;
  // stage dest row = i*32 + wave*8 + (lane>>3): r&4 = lane&32-bit, r&8 = wave&1
  const int lrow = lane >> 3;
  const int lcol = (((lane & 7) << 3) ^ ((lane & 32) >> 1) ^ ((wave & 1) << 5));

  const int fr = lane & 15;
  const int fq = lane >> 4;
  const int esw = ((fr & 4) << 2) ^ ((fr & 8) << 2);  // element-XOR from row bits

  f32x4 acc[MR][NR] = {};

  for (int k0 = 0; k0 < K; k0 += BK) {
#pragma unroll
    for (int i = 0; i < BM / RPL; ++i) {
      const int rb = i * RPL + wave * RPW;
      gload_lds16(&A[(size_t)(bm + rb + lrow) * lda + k0 + lcol], &As[rb][0]);
    }
#pragma unroll
    for (int i = 0; i < BN / RPL; ++i) {
      const int rb = i * RPL + wave * RPW;
      gload_lds16(&BT[(size_t)(bn + rb + lrow) * K + k0 + lcol], &Bs[rb][0]);
    }
    __syncthreads();
#pragma unroll
    for (int kk = 0; kk < BK / 32; ++kk) {
      bf16x8 af[MR], bfr[NR];
      const int ecol = (kk * 32 + fq * 8) ^ esw;
#pragma unroll
      for (int m = 0; m < MR; ++m)
        af[m] = *(const bf16x8*)&As[wr * (BM / WROWS) + m * 16 + fr][ecol];
#pragma unroll
      for (int n = 0; n < NR; ++n)
        bfr[n] = *(const bf16x8*)&Bs[wc * (BN / WCOLS) + n * 16 + fr][ecol];
#pragma unroll
      for (int m = 0; m < MR; ++m)
#pragma unroll
        for (int n = 0; n < NR; ++n)
          acc[m][n] = __builtin_amdgcn_mfma_f32_16x16x32_bf16(
              af[m], bfr[n], acc[m][n], 0, 0, 0);
    }
    __syncthreads();
  }

#pragma unroll
  for (int n = 0; n < NR; ++n) {
    const int gcol = bn + wc * (BN / WCOLS) + n * 16 + fr;
    const float bv = bias[gcol] + t * wtime[gcol];
#pragma unroll
    for (int m = 0; m < MR; ++m) {
      const int grow0 = bm + wr * (BM / WROWS) + m * 16 + (fq << 2);
#pragma unroll
      for (int r = 0; r < 4; ++r) {
        float v = acc[m][n][r] + bv;
        if (RELU) v = v > 0.0f ? v : 0.0f;
        if constexpr (OUT_BF16)
          ((bf16_t*)Cv)[(size_t)(grow0 + r) * ldc + gcol] = (bf16_t)v;
        else
          ((float*)Cv)[(size_t)(grow0 + r) * ldc + gcol] = v;
      }
    }
  }
}

// ---------------------------------------------------------------------------
// Layer 4 (N=64, K=1024) with RK4 combine fused into the epilogue.
// BM=64, BN=64, 4 waves (2x2) -> 512 blocks = 2 blocks/CU.  Swizzled LDS.
// ---------------------------------------------------------------------------
__global__ __launch_bounds__(256) void gemm_l4_rk4(
    const bf16_t* __restrict__ A, int lda,
    const bf16_t* __restrict__ BT,
    const float* __restrict__ bias,
    const float* __restrict__ wtime,
    float t,
    float* __restrict__ y, float* __restrict__ accb,
    bf16_t* __restrict__ ybf,
    float ca, float cs, int mode,
    int M, int K)
{
  constexpr int BM = 64, BN = 64, BK = 64;
  constexpr int MR = 2, NR = 2;

  __shared__ bf16_t As[BM][BK];
  __shared__ bf16_t Bs[BN][BK];

  const int tid  = threadIdx.x;
  const int wave = tid >> 6;
  const int lane = tid & 63;
  const int wr = wave >> 1;
  const int wc = wave & 1;
  const int bm = blockIdx.x * BM;
  const int lrow = lane >> 3;
  const int lcol = (((lane & 7) << 3) ^ ((lane & 32) >> 1) ^ ((wave & 1) << 5));

  const int fr = lane & 15;
  const int fq = lane >> 4;
  const int esw = ((fr & 4) << 2) ^ ((fr & 8) << 2);

  f32x4 acc[MR][NR] = {};

  for (int k0 = 0; k0 < K; k0 += BK) {
#pragma unroll
    for (int i = 0; i < 2; ++i) {
      const int rb = i * 32 + wave * 8;
      gload_lds16(&A[(size_t)(bm + rb + lrow) * lda + k0 + lcol], &As[rb][0]);
    }
#pragma unroll
    for (int i = 0; i < 2; ++i) {
      const int rb = i * 32 + wave * 8;
      gload_lds16(&BT[(size_t)(rb + lrow) * K + k0 + lcol], &Bs[rb][0]);
    }
    __syncthreads();
#pragma unroll
    for (int kk = 0; kk < 2; ++kk) {
      bf16x8 af[MR], bfr[NR];
      const int ecol = (kk * 32 + fq * 8) ^ esw;
#pragma unroll
      for (int m = 0; m < MR; ++m)
        af[m] = *(const bf16x8*)&As[wr * 32 + m * 16 + fr][ecol];
#pragma unroll
      for (int n = 0; n < NR; ++n)
        bfr[n] = *(const bf16x8*)&Bs[wc * 32 + n * 16 + fr][ecol];
#pragma unroll
      for (int m = 0; m < MR; ++m)
#pragma unroll
        for (int n = 0; n < NR; ++n)
          acc[m][n] = __builtin_amdgcn_mfma_f32_16x16x32_bf16(
              af[m], bfr[n], acc[m][n], 0, 0, 0);
    }
    __syncthreads();
  }

#pragma unroll
  for (int n = 0; n < NR; ++n) {
    const int gcol = wc * 32 + n * 16 + fr;
    const float bv = bias[gcol] + t * wtime[gcol];
#pragma unroll
    for (int m = 0; m < MR; ++m) {
      const int grow0 = bm + wr * 32 + m * 16 + (fq << 2);
#pragma unroll
      for (int r = 0; r < 4; ++r) {
        const float kv = acc[m][n][r] + bv;
        const size_t o = (size_t)(grow0 + r) * 64 + gcol;
        if (mode == 0) {
          accb[o] = kv;
          ybf[o] = (bf16_t)(y[o] + cs * kv);
        } else if (mode == 1) {
          accb[o] += ca * kv;
          ybf[o] = (bf16_t)(y[o] + cs * kv);
        } else {
          const float ny = y[o] + cs * (accb[o] + kv);
          y[o] = ny;
          ybf[o] = (bf16_t)ny;
        }
      }
    }
  }
}

// ---------------------------------------------------------------------------
__global__ void prep_weight(const float* __restrict__ W, const float* __restrict__ b,
                            bf16_t* __restrict__ WT, float* __restrict__ bias,
                            float* __restrict__ wtime,
                            int K, int N, int Kpad, int Npad)
{
  int idx = blockIdx.x * 256 + threadIdx.x;
  int total = Npad * Kpad;
  if (idx < total) {
    int n = idx / Kpad, k = idx % Kpad;
    float v = (n < N && k < K) ? W[(size_t)k * N + n] : 0.0f;
    WT[idx] = (bf16_t)v;
  }
  if (idx < Npad) {
    bias[idx]  = (idx < N) ? b[idx] : 0.0f;
    wtime[idx] = (idx < N) ? W[(size_t)K * N + idx] : 0.0f;
  }
}

__global__ void init_y(const float* __restrict__ x, float* __restrict__ y,
                       bf16_t* __restrict__ ybf, int M)
{
  int i = blockIdx.x * 256 + threadIdx.x;
  if (i < M * 64) {
    int m = i >> 6, c = i & 63;
    float v = (c < 2) ? x[m * 2 + c] : 0.0f;
    y[i] = v;
    ybf[i] = (bf16_t)v;
  }
}

__global__ void extract_out(const float* __restrict__ y, float* __restrict__ out, int M)
{
  int i = blockIdx.x * 256 + threadIdx.x;
  if (i < M * 3) {
    int m = i / 3, c = i % 3;
    out[i] = y[(size_t)m * 64 + c];
  }
}

extern "C" void kernel_launch(void* const* d_in, const int* in_sizes, int n_in,
                              void* d_out, int out_size, void* d_ws, size_t ws_size,
                              hipStream_t stream)
{
  (void)in_sizes; (void)n_in; (void)out_size; (void)ws_size;
  const int M = 32768;

  const float* x = (const float*)d_in[0];
  const float* Wp[5]; const float* bp[5];
  for (int i = 0; i < 5; ++i) {
    Wp[i] = (const float*)d_in[1 + 2 * i];
    bp[i] = (const float*)d_in[2 + 2 * i];
  }

  char* ws = (char*)d_ws; size_t off = 0;
  auto alloc = [&](size_t bytes) -> char* {
    char* p = ws + off; off += (bytes + 255) & ~(size_t)255; return p;
  };

  bf16_t* WT[5];
  WT[0] = (bf16_t*)alloc((size_t)1024 * 64 * 2);
  WT[1] = (bf16_t*)alloc((size_t)1024 * 1024 * 2);
  WT[2] = (bf16_t*)alloc((size_t)1024 * 1024 * 2);
  WT[3] = (bf16_t*)alloc((size_t)1024 * 1024 * 2);
  WT[4] = (bf16_t*)alloc((size_t)64 * 1024 * 2);
  float* bias[5]; float* wtm[5];
  for (int i = 0; i < 5; ++i) {
    int Np = (i == 4) ? 64 : 1024;
    bias[i] = (float*)alloc((size_t)Np * 4);
    wtm[i]  = (float*)alloc((size_t)Np * 4);
  }
  float*  y    = (float*)alloc((size_t)M * 64 * 4);
  float*  accb = (float*)alloc((size_t)M * 64 * 4);
  bf16_t* ybf  = (bf16_t*)alloc((size_t)M * 64 * 2);
  bf16_t* act0 = (bf16_t*)alloc((size_t)M * 1024 * 2);
  bf16_t* act1 = (bf16_t*)alloc((size_t)M * 1024 * 2);

  const int Kd[5]  = {50, 1024, 1024, 1024, 1024};
  const int Nd[5]  = {1024, 1024, 1024, 1024, 50};
  const int Kpd[5] = {64, 1024, 1024, 1024, 1024};
  const int Npd[5] = {1024, 1024, 1024, 1024, 64};
  for (int i = 0; i < 5; ++i) {
    int tot = Npd[i] * Kpd[i];
    prep_weight<<<dim3((tot + 255) / 256), 256, 0, stream>>>(
        Wp[i], bp[i], WT[i], bias[i], wtm[i], Kd[i], Nd[i], Kpd[i], Npd[i]);
  }

  init_y<<<dim3((M * 64 + 255) / 256), 256, 0, stream>>>(x, y, ybf, M);

  const float dtv = 1.0f / 32.0f;
  dim3 gL0(M / 128, 1024 / 128);        // 2048 blocks
  dim3 g256(M / 256 * (1024 / 256));    // 512 blocks, %8 == 0
  dim3 gL4(M / 64);                     // 512 blocks = 2/CU

  auto run_net = [&](float t, float ca, float cs, int mode) {
    gemm_bt<128,128,64,2,2,true,true><<<gL0, 256, 0, stream>>>(
        ybf, 64, WT[0], bias[0], wtm[0], t, act0, 1024, M, 64);
    gemm256<1024><<<g256, 512, 0, stream>>>(
        act0, WT[1], bias[1], wtm[1], t, act1, 1024, M, 1024);
    gemm256<1024><<<g256, 512, 0, stream>>>(
        act1, WT[2], bias[2], wtm[2], t, act0, 1024, M, 1024);
    gemm256<1024><<<g256, 512, 0, stream>>>(
        act0, WT[3], bias[3], wtm[3], t, act1, 1024, M, 1024);
    gemm_l4_rk4<<<gL4, 256, 0, stream>>>(
        act1, 1024, WT[4], bias[4], wtm[4], t,
        y, accb, ybf, ca, cs, mode, M, 1024);
  };

  for (int i = 0; i < 32; ++i) {
    const float t0 = i * dtv;
    const float tm = t0 + 0.5f * dtv;
    const float t1 = t0 + dtv;
    run_net(t0, 0.0f, 0.5f * dtv, 0);   // k1
    run_net(tm, 2.0f, 0.5f * dtv, 1);   // k2
    run_net(tm, 2.0f, dtv,        1);   // k3
    run_net(t1, 0.0f, dtv / 6.0f, 2);   // k4
  }

  extract_out<<<dim3((M * 3 + 255) / 256), 256, 0, stream>>>(y, (float*)d_out, M);
}

// Round 5
// 39347.195 us; speedup vs baseline: 1.2656x; 1.0009x over previous
//
#include <hip/hip_runtime.h>
#include <hip/hip_bf16.h>
#include <stdint.h>

// Neural ODE (RK4, 32 steps) over a 5-layer MLP, B=32768, VAR_DIM=50 (pad 64).
// bf16 MFMA GEMMs (16x16x32), fp32 accum, fp32 state y.
// concat(h,t) @ W == h @ W[:K] + (b + t*W[K]) -> time column folded into bias.
// r4: full bank-spread LDS swizzle (byte bit5 ^= row&4, bit6 ^= row&8) on all
//     GEMM kernels -- previous bit5-only swizzle left 16 claims/bank (2x floor).

typedef __bf16 bf16_t;
typedef bf16_t bf16x8 __attribute__((ext_vector_type(8)));
typedef float  f32x4  __attribute__((ext_vector_type(4)));

#define DEVI static __device__ __forceinline__

DEVI void gload_lds16(const bf16_t* gsrc, bf16_t* ldst) {
  __builtin_amdgcn_global_load_lds(
      (const __attribute__((address_space(1))) uint32_t*)gsrc,
      (__attribute__((address_space(3))) uint32_t*)ldst,
      16, 0, 0);
}

// ---------------------------------------------------------------------------
// 256x256 tile, BK=64, 8 waves (2Mx4N), double-buffered LDS, 8-phase schedule.
// LDS swizzle: physical_col_byte = logical ^ 32*(row&4?1:0) ^ 64*(row&8?1:0).
// Staged via linear global_load_lds dest + pre-swizzled global SOURCE col;
// read with the same XOR on the ds_read byte address.
// vmcnt(4) once per K-tile (2 half-tiles in flight); drain only in tail.
// ---------------------------------------------------------------------------
template<int K>
__global__ __launch_bounds__(512, 2) void gemm256(
    const bf16_t* __restrict__ A,     // M x K row-major
    const bf16_t* __restrict__ BT,    // N x K row-major (pre-transposed W)
    const float* __restrict__ bias,
    const float* __restrict__ wtime,
    float t,
    bf16_t* __restrict__ C, int ldc,
    int M, int N)
{
  constexpr int NT = K / 64;          // K-tiles
  static_assert(NT >= 2, "need >=2 K-tiles");

  __shared__ __align__(16) bf16_t As[2][256][64];
  __shared__ __align__(16) bf16_t Bs[2][256][64];

  const int tid  = threadIdx.x;
  const int wave = tid >> 6;
  const int lane = tid & 63;
  const int wr = wave >> 2;           // 0..1 -> 128-row half
  const int wc = wave & 3;            // 0..3 -> 64-col strip

  // T1: XCD-aware bijective swizzle (gridDim.x % 8 == 0 by construction)
  int wg = blockIdx.x;
  {
    const int cpx = gridDim.x >> 3;
    wg = (wg & 7) * cpx + (wg >> 3);
  }
  const int nbn = N >> 8;
  const int bm = (wg / nbn) << 8;
  const int bn = (wg % nbn) << 8;

  // staging: dest row r = [buf*256 + h*128 +] wave*8 + (lane>>3)
  //   -> r&4 = lane&32-bit, r&8 = wave&1.  Pre-swizzle the SOURCE col:
  //   elem ^= ((lane&32)>>1)  (byte bit5)  ^ ((wave&1)<<5)  (byte bit6)
  const int srow = lane >> 3;
  const int scol = ((lane & 7) << 3) ^ ((lane & 32) >> 1) ^ ((wave & 1) << 5);
  const bf16_t* aS = A  + (size_t)(bm + wave * 8 + srow) * K + scol;
  const bf16_t* bS = BT + (size_t)(bn + wave * 8 + srow) * K + scol;
  bf16_t* aD = &As[0][0][0] + wave * 8 * 64;   // wave-uniform LDS base
  bf16_t* bD = &Bs[0][0][0] + wave * 8 * 64;

  // stage one half-tile (128 rows x 64 cols) = 2 load instrs
  auto stageHalf = [&](int kt, int isB, int h) {
    const int buf = kt & 1;
    const bf16_t* src = (isB ? bS : aS) + (size_t)(h * 128) * K + kt * 64;
    bf16_t*       dst = (isB ? bD : aD) + (buf * 256 + h * 128) * 64;
    gload_lds16(src,                 dst);
    gload_lds16(src + (size_t)64 * K, dst + 64 * 64);
  };

  const int fr = lane & 15;
  const int fq = lane >> 4;
  const int rsw = ((fr & 4) << 3) ^ ((fr & 8) << 3);   // byte-XOR from row bits

  bf16x8 af[8];        // A quadrant frags [m*2+kk]
  bf16x8 bfr[8];       // B frags [nh*4 + n*2 + kk]
  f32x4  acc[8][4] = {};

  auto lda_frag = [&](int buf, int mh) {
    const char* base = (const char*)&As[buf][0][0];
#pragma unroll
    for (int m = 0; m < 4; ++m)
#pragma unroll
      for (int kk = 0; kk < 2; ++kk) {
        int r  = wr * 128 + (mh * 4 + m) * 16 + fr;
        int cb = (kk * 64 + fq * 16) ^ rsw;
        af[m * 2 + kk] = *(const bf16x8*)(base + r * 128 + cb);
      }
  };
  auto ldb_frag = [&](int buf, int nh) {
    const char* base = (const char*)&Bs[buf][0][0];
#pragma unroll
    for (int n = 0; n < 2; ++n)
#pragma unroll
      for (int kk = 0; kk < 2; ++kk) {
        int r  = wc * 64 + (nh * 2 + n) * 16 + fr;
        int cb = (kk * 64 + fq * 16) ^ rsw;
        bfr[nh * 4 + n * 2 + kk] = *(const bf16x8*)(base + r * 128 + cb);
      }
  };
  auto mma_quad = [&](int mh, int nh) {
    __builtin_amdgcn_s_setprio(1);
#pragma unroll
    for (int m = 0; m < 4; ++m)
#pragma unroll
      for (int n = 0; n < 2; ++n)
#pragma unroll
        for (int kk = 0; kk < 2; ++kk)
          acc[mh * 4 + m][nh * 2 + n] = __builtin_amdgcn_mfma_f32_16x16x32_bf16(
              af[m * 2 + kk], bfr[nh * 4 + n * 2 + kk],
              acc[mh * 4 + m][nh * 2 + n], 0, 0, 0);
    __builtin_amdgcn_s_setprio(0);
  };

  // prologue: tile0 full + tile1 {Bh0, Ah0}  (matches steady-state p2/p3 order)
  stageHalf(0, 0, 0); stageHalf(0, 1, 0);
  stageHalf(0, 0, 1); stageHalf(0, 1, 1);
  stageHalf(1, 1, 0); stageHalf(1, 0, 0);
  asm volatile("s_waitcnt vmcnt(4)" ::: "memory");   // tile0 resident
  __builtin_amdgcn_s_barrier();

  for (int t2 = 0; t2 < NT; ++t2) {
    const int buf = t2 & 1;
    // phase 0: quadrant (0,0); stage Ah1(t2+1) -> other buf
    lda_frag(buf, 0);
    ldb_frag(buf, 0);
    if (t2 + 1 < NT) stageHalf(t2 + 1, 0, 1);
    asm volatile("s_waitcnt lgkmcnt(8)" ::: "memory");
    __builtin_amdgcn_s_barrier();
    asm volatile("s_waitcnt lgkmcnt(0)" ::: "memory");
    mma_quad(0, 0);
    __builtin_amdgcn_s_barrier();
    // phase 1: quadrant (0,1); stage Bh1(t2+1) -> other buf
    ldb_frag(buf, 1);
    if (t2 + 1 < NT) stageHalf(t2 + 1, 1, 1);
    __builtin_amdgcn_s_barrier();
    asm volatile("s_waitcnt lgkmcnt(0)" ::: "memory");
    mma_quad(0, 1);
    __builtin_amdgcn_s_barrier();
    // phase 2: quadrant (1,0); stage Bh0(t2+2) -> current buf (B last read p1)
    lda_frag(buf, 1);
    if (t2 + 2 < NT) stageHalf(t2 + 2, 1, 0);
    __builtin_amdgcn_s_barrier();
    asm volatile("s_waitcnt lgkmcnt(0)" ::: "memory");
    mma_quad(1, 0);
    __builtin_amdgcn_s_barrier();
    // phase 3: quadrant (1,1); stage Ah0(t2+2) -> current buf (A last read p2)
    if (t2 + 2 < NT) {
      stageHalf(t2 + 2, 0, 0);
      asm volatile("s_waitcnt vmcnt(4)" ::: "memory");  // tile t2+1 resident
    } else {
      asm volatile("s_waitcnt vmcnt(0)" ::: "memory");
    }
    __builtin_amdgcn_s_barrier();
    mma_quad(1, 1);
    __builtin_amdgcn_s_barrier();
  }

  // epilogue: bias(t) + ReLU, bf16 out
#pragma unroll
  for (int n = 0; n < 4; ++n) {
    const int gcol = bn + wc * 64 + n * 16 + fr;
    const float bv = bias[gcol] + t * wtime[gcol];
#pragma unroll
    for (int m = 0; m < 8; ++m) {
      const int grow0 = bm + wr * 128 + m * 16 + (fq << 2);
#pragma unroll
      for (int r = 0; r < 4; ++r) {
        float v = acc[m][n][r] + bv;
        v = v > 0.0f ? v : 0.0f;
        C[(size_t)(grow0 + r) * ldc + gcol] = (bf16_t)v;
      }
    }
  }
}

// ---------------------------------------------------------------------------
// 128^2 kernel for layer 0 (K=64), now with the full bank-spread swizzle.
// ---------------------------------------------------------------------------
template<int BM, int BN, int BK, int WROWS, int WCOLS, bool RELU, bool OUT_BF16>
__global__ __launch_bounds__(256) void gemm_bt(
    const bf16_t* __restrict__ A, int lda,
    const bf16_t* __restrict__ BT,
    const float* __restrict__ bias,
    const float* __restrict__ wtime,
    float t,
    void* __restrict__ Cv, int ldc,
    int M, int K)
{
  static_assert(BK == 64, "swizzle assumes BK=64");
  constexpr int MR  = BM / WROWS / 16;
  constexpr int NR  = BN / WCOLS / 16;
  constexpr int TPR = BK / 8;        // 8
  constexpr int RPW = 64 / TPR;      // 8
  constexpr int RPL = 4 * RPW;       // 32
  static_assert(BM % RPL == 0 && BN % RPL == 0, "tile staging mismatch");

  __shared__ bf16_t As[BM][BK];
  __shared__ bf16_t Bs[BN][BK];

  const int tid  = threadIdx.x;
  const int wave = tid >> 6;
  const int lane = tid & 63;
  const int wr = wave / WCOLS;
  const int wc = wave % WCOLS;
  const int bm = blockIdx.x * BM;
  const int bn = blockIdx.y * BN;
  // stage dest row = i*32 + wave*8 + (lane>>3): r&4 = lane&32-bit, r&8 = wave&1
  const int lrow = lane >> 3;
  const int lcol = (((lane & 7) << 3) ^ ((lane & 32) >> 1) ^ ((wave & 1) << 5));

  const int fr = lane & 15;
  const int fq = lane >> 4;
  const int esw = ((fr & 4) << 2) ^ ((fr & 8) << 2);  // element-XOR from row bits

  f32x4 acc[MR][NR] = {};

  for (int k0 = 0; k0 < K; k0 += BK) {
#pragma unroll
    for (int i = 0; i < BM / RPL; ++i) {
      const int rb = i * RPL + wave * RPW;
      gload_lds16(&A[(size_t)(bm + rb + lrow) * lda + k0 + lcol], &As[rb][0]);
    }
#pragma unroll
    for (int i = 0; i < BN / RPL; ++i) {
      const int rb = i * RPL + wave * RPW;
      gload_lds16(&BT[(size_t)(bn + rb + lrow) * K + k0 + lcol], &Bs[rb][0]);
    }
    __syncthreads();
#pragma unroll
    for (int kk = 0; kk < BK / 32; ++kk) {
      bf16x8 af[MR], bfr[NR];
      const int ecol = (kk * 32 + fq * 8) ^ esw;
#pragma unroll
      for (int m = 0; m < MR; ++m)
        af[m] = *(const bf16x8*)&As[wr * (BM / WROWS) + m * 16 + fr][ecol];
#pragma unroll
      for (int n = 0; n < NR; ++n)
        bfr[n] = *(const bf16x8*)&Bs[wc * (BN / WCOLS) + n * 16 + fr][ecol];
#pragma unroll
      for (int m = 0; m < MR; ++m)
#pragma unroll
        for (int n = 0; n < NR; ++n)
          acc[m][n] = __builtin_amdgcn_mfma_f32_16x16x32_bf16(
              af[m], bfr[n], acc[m][n], 0, 0, 0);
    }
    __syncthreads();
  }

#pragma unroll
  for (int n = 0; n < NR; ++n) {
    const int gcol = bn + wc * (BN / WCOLS) + n * 16 + fr;
    const float bv = bias[gcol] + t * wtime[gcol];
#pragma unroll
    for (int m = 0; m < MR; ++m) {
      const int grow0 = bm + wr * (BM / WROWS) + m * 16 + (fq << 2);
#pragma unroll
      for (int r = 0; r < 4; ++r) {
        float v = acc[m][n][r] + bv;
        if (RELU) v = v > 0.0f ? v : 0.0f;
        if constexpr (OUT_BF16)
          ((bf16_t*)Cv)[(size_t)(grow0 + r) * ldc + gcol] = (bf16_t)v;
        else
          ((float*)Cv)[(size_t)(grow0 + r) * ldc + gcol] = v;
      }
    }
  }
}

// ---------------------------------------------------------------------------
// Layer 4 (N=64, K=1024) with RK4 combine fused into the epilogue.
// BM=64, BN=64, 4 waves (2x2) -> 512 blocks = 2 blocks/CU.  Swizzled LDS.
// ---------------------------------------------------------------------------
__global__ __launch_bounds__(256) void gemm_l4_rk4(
    const bf16_t* __restrict__ A, int lda,
    const bf16_t* __restrict__ BT,
    const float* __restrict__ bias,
    const float* __restrict__ wtime,
    float t,
    float* __restrict__ y, float* __restrict__ accb,
    bf16_t* __restrict__ ybf,
    float ca, float cs, int mode,
    int M, int K)
{
  constexpr int BM = 64, BN = 64, BK = 64;
  constexpr int MR = 2, NR = 2;

  __shared__ bf16_t As[BM][BK];
  __shared__ bf16_t Bs[BN][BK];

  const int tid  = threadIdx.x;
  const int wave = tid >> 6;
  const int lane = tid & 63;
  const int wr = wave >> 1;
  const int wc = wave & 1;
  const int bm = blockIdx.x * BM;
  const int lrow = lane >> 3;
  const int lcol = (((lane & 7) << 3) ^ ((lane & 32) >> 1) ^ ((wave & 1) << 5));

  const int fr = lane & 15;
  const int fq = lane >> 4;
  const int esw = ((fr & 4) << 2) ^ ((fr & 8) << 2);

  f32x4 acc[MR][NR] = {};

  for (int k0 = 0; k0 < K; k0 += BK) {
#pragma unroll
    for (int i = 0; i < 2; ++i) {
      const int rb = i * 32 + wave * 8;
      gload_lds16(&A[(size_t)(bm + rb + lrow) * lda + k0 + lcol], &As[rb][0]);
    }
#pragma unroll
    for (int i = 0; i < 2; ++i) {
      const int rb = i * 32 + wave * 8;
      gload_lds16(&BT[(size_t)(rb + lrow) * K + k0 + lcol], &Bs[rb][0]);
    }
    __syncthreads();
#pragma unroll
    for (int kk = 0; kk < 2; ++kk) {
      bf16x8 af[MR], bfr[NR];
      const int ecol = (kk * 32 + fq * 8) ^ esw;
#pragma unroll
      for (int m = 0; m < MR; ++m)
        af[m] = *(const bf16x8*)&As[wr * 32 + m * 16 + fr][ecol];
#pragma unroll
      for (int n = 0; n < NR; ++n)
        bfr[n] = *(const bf16x8*)&Bs[wc * 32 + n * 16 + fr][ecol];
#pragma unroll
      for (int m = 0; m < MR; ++m)
#pragma unroll
        for (int n = 0; n < NR; ++n)
          acc[m][n] = __builtin_amdgcn_mfma_f32_16x16x32_bf16(
              af[m], bfr[n], acc[m][n], 0, 0, 0);
    }
    __syncthreads();
  }

#pragma unroll
  for (int n = 0; n < NR; ++n) {
    const int gcol = wc * 32 + n * 16 + fr;
    const float bv = bias[gcol] + t * wtime[gcol];
#pragma unroll
    for (int m = 0; m < MR; ++m) {
      const int grow0 = bm + wr * 32 + m * 16 + (fq << 2);
#pragma unroll
      for (int r = 0; r < 4; ++r) {
        const float kv = acc[m][n][r] + bv;
        const size_t o = (size_t)(grow0 + r) * 64 + gcol;
        if (mode == 0) {
          accb[o] = kv;
          ybf[o] = (bf16_t)(y[o] + cs * kv);
        } else if (mode == 1) {
          accb[o] += ca * kv;
          ybf[o] = (bf16_t)(y[o] + cs * kv);
        } else {
          const float ny = y[o] + cs * (accb[o] + kv);
          y[o] = ny;
          ybf[o] = (bf16_t)ny;
        }
      }
    }
  }
}

// ---------------------------------------------------------------------------
__global__ void prep_weight(const float* __restrict__ W, const float* __restrict__ b,
                            bf16_t* __restrict__ WT, float* __restrict__ bias,
                            float* __restrict__ wtime,
                            int K, int N, int Kpad, int Npad)
{
  int idx = blockIdx.x * 256 + threadIdx.x;
  int total = Npad * Kpad;
  if (idx < total) {
    int n = idx / Kpad, k = idx % Kpad;
    float v = (n < N && k < K) ? W[(size_t)k * N + n] : 0.0f;
    WT[idx] = (bf16_t)v;
  }
  if (idx < Npad) {
    bias[idx]  = (idx < N) ? b[idx] : 0.0f;
    wtime[idx] = (idx < N) ? W[(size_t)K * N + idx] : 0.0f;
  }
}

__global__ void init_y(const float* __restrict__ x, float* __restrict__ y,
                       bf16_t* __restrict__ ybf, int M)
{
  int i = blockIdx.x * 256 + threadIdx.x;
  if (i < M * 64) {
    int m = i >> 6, c = i & 63;
    float v = (c < 2) ? x[m * 2 + c] : 0.0f;
    y[i] = v;
    ybf[i] = (bf16_t)v;
  }
}

__global__ void extract_out(const float* __restrict__ y, float* __restrict__ out, int M)
{
  int i = blockIdx.x * 256 + threadIdx.x;
  if (i < M * 3) {
    int m = i / 3, c = i % 3;
    out[i] = y[(size_t)m * 64 + c];
  }
}

extern "C" void kernel_launch(void* const* d_in, const int* in_sizes, int n_in,
                              void* d_out, int out_size, void* d_ws, size_t ws_size,
                              hipStream_t stream)
{
  (void)in_sizes; (void)n_in; (void)out_size; (void)ws_size;
  const int M = 32768;

  const float* x = (const float*)d_in[0];
  const float* Wp[5]; const float* bp[5];
  for (int i = 0; i < 5; ++i) {
    Wp[i] = (const float*)d_in[1 + 2 * i];
    bp[i] = (const float*)d_in[2 + 2 * i];
  }

  char* ws = (char*)d_ws; size_t off = 0;
  auto alloc = [&](size_t bytes) -> char* {
    char* p = ws + off; off += (bytes + 255) & ~(size_t)255; return p;
  };

  bf16_t* WT[5];
  WT[0] = (bf16_t*)alloc((size_t)1024 * 64 * 2);
  WT[1] = (bf16_t*)alloc((size_t)1024 * 1024 * 2);
  WT[2] = (bf16_t*)alloc((size_t)1024 * 1024 * 2);
  WT[3] = (bf16_t*)alloc((size_t)1024 * 1024 * 2);
  WT[4] = (bf16_t*)alloc((size_t)64 * 1024 * 2);
  float* bias[5]; float* wtm[5];
  for (int i = 0; i < 5; ++i) {
    int Np = (i == 4) ? 64 : 1024;
    bias[i] = (float*)alloc((size_t)Np * 4);
    wtm[i]  = (float*)alloc((size_t)Np * 4);
  }
  float*  y    = (float*)alloc((size_t)M * 64 * 4);
  float*  accb = (float*)alloc((size_t)M * 64 * 4);
  bf16_t* ybf  = (bf16_t*)alloc((size_t)M * 64 * 2);
  bf16_t* act0 = (bf16_t*)alloc((size_t)M * 1024 * 2);
  bf16_t* act1 = (bf16_t*)alloc((size_t)M * 1024 * 2);

  const int Kd[5]  = {50, 1024, 1024, 1024, 1024};
  const int Nd[5]  = {1024, 1024, 1024, 1024, 50};
  const int Kpd[5] = {64, 1024, 1024, 1024, 1024};
  const int Npd[5] = {1024, 1024, 1024, 1024, 64};
  for (int i = 0; i < 5; ++i) {
    int tot = Npd[i] * Kpd[i];
    prep_weight<<<dim3((tot + 255) / 256), 256, 0, stream>>>(
        Wp[i], bp[i], WT[i], bias[i], wtm[i], Kd[i], Nd[i], Kpd[i], Npd[i]);
  }

  init_y<<<dim3((M * 64 + 255) / 256), 256, 0, stream>>>(x, y, ybf, M);

  const float dtv = 1.0f / 32.0f;
  dim3 gL0(M / 128, 1024 / 128);        // 2048 blocks
  dim3 g256(M / 256 * (1024 / 256));    // 512 blocks, %8 == 0
  dim3 gL4(M / 64);                     // 512 blocks = 2/CU

  auto run_net = [&](float t, float ca, float cs, int mode) {
    gemm_bt<128,128,64,2,2,true,true><<<gL0, 256, 0, stream>>>(
        ybf, 64, WT[0], bias[0], wtm[0], t, act0, 1024, M, 64);
    gemm256<1024><<<g256, 512, 0, stream>>>(
        act0, WT[1], bias[1], wtm[1], t, act1, 1024, M, 1024);
    gemm256<1024><<<g256, 512, 0, stream>>>(
        act1, WT[2], bias[2], wtm[2], t, act0, 1024, M, 1024);
    gemm256<1024><<<g256, 512, 0, stream>>>(
        act0, WT[3], bias[3], wtm[3], t, act1, 1024, M, 1024);
    gemm_l4_rk4<<<gL4, 256, 0, stream>>>(
        act1, 1024, WT[4], bias[4], wtm[4], t,
        y, accb, ybf, ca, cs, mode, M, 1024);
  };

  for (int i = 0; i < 32; ++i) {
    const float t0 = i * dtv;
    const float tm = t0 + 0.5f * dtv;
    const float t1 = t0 + dtv;
    run_net(t0, 0.0f, 0.5f * dtv, 0);   // k1
    run_net(tm, 2.0f, 0.5f * dtv, 1);   // k2
    run_net(tm, 2.0f, dtv,        1);   // k3
    run_net(t1, 0.0f, dtv / 6.0f, 2);   // k4
  }

  extract_out<<<dim3((M * 3 + 255) / 256), 256, 0, stream>>>(y, (float*)d_out, M);
}